// Round 5
// baseline (511.411 us; speedup 1.0000x reference)
//
#include <hip/hip_runtime.h>
#include <hip/hip_bf16.h>

#define N_NODES 200000
#define N_EDGES 1200000
#define IN_DIM  128
#define HID     64
#define NGRAPH  1024
#define NCLS    6
#define BN_EPS  1e-5f

#define TILE_N   64
#define ZS       68          // Ztmp row stride (floats); 272B = 17 banks shift, 2-way max
#define ECAP     1024

#define SCAN_CHUNK 1024
#define NBLK_SCAN ((N_NODES + SCAN_CHUNK - 1) / SCAN_CHUNK)   // 196

// ---- binned CSR build ----
#define NBKT   128           // dst-range buckets
#define BRANGE 1568          // nodes per bucket (128*1568 = 200704 >= N)
#define BCAP   12288         // per-bucket edge capacity (mean 9408, sigma ~97)
#define EPB    4096          // edges per bin_kernel block
#define NB_BIN ((N_EDGES + EPB - 1) / EPB)   // 293
// packed ebin entry: src (18b) | dstLocal (11b) << 18

// 16B-slot XOR swizzle for A-frag LDS
#define SWZ(s) ((s) ^ (((s) >> 4) & 3))

typedef short bf16x8 __attribute__((ext_vector_type(8)));
typedef float f32x4  __attribute__((ext_vector_type(4)));
#define MFMA16(a,b,c) __builtin_amdgcn_mfma_f32_16x16x32_bf16((a),(b),(c),0,0,0)

__device__ __forceinline__ unsigned short f2bf(float f) {
    union { __hip_bfloat16 h; unsigned short u; } v; v.h = __float2bfloat16(f); return v.u;
}
__device__ __forceinline__ float bfbits2f(unsigned short u) {
    union { unsigned int i; float f; } v; v.i = ((unsigned int)u) << 16; return v.f;
}
// f32x4 -> (hi bf16x4, lo bf16x4) packed as uint2 each
__device__ __forceinline__ void cvt4(const f32x4& x, uint2& hi, uint2& lo) {
    const unsigned short h0 = f2bf(x[0]), h1 = f2bf(x[1]), h2 = f2bf(x[2]), h3 = f2bf(x[3]);
    hi.x = (unsigned)h0 | ((unsigned)h1 << 16);
    hi.y = (unsigned)h2 | ((unsigned)h3 << 16);
    const unsigned short l0 = f2bf(x[0] - bfbits2f(h0)), l1 = f2bf(x[1] - bfbits2f(h1));
    const unsigned short l2 = f2bf(x[2] - bfbits2f(h2)), l3 = f2bf(x[3] - bfbits2f(h3));
    lo.x = (unsigned)l0 | ((unsigned)l1 << 16);
    lo.y = (unsigned)l2 | ((unsigned)l3 << 16);
}

// ===========================================================================
// Setup kernel: prep_emb (blocks 0..63) + prep_fc (64..255) + graph_offs /
// gcnt zero (256..260). Weight B-frag packing, bf16 hi/lo planes.
// ===========================================================================
__global__ __launch_bounds__(256) void setup_kernel(
    const float* __restrict__ emb_w, unsigned short* __restrict__ wpe,
    const float* __restrict__ fc1, const float* __restrict__ fc2,
    unsigned short* __restrict__ wpf,
    const int* __restrict__ batch, int* __restrict__ goffs,
    int* __restrict__ gcnt)
{
    const int b = blockIdx.x, t = threadIdx.x;
    if (b < 64) {
        const int idx = b * 256 + t;                     // [ct2][s2][p1][l6][j3]
        const int j = idx & 7, l = (idx >> 3) & 63;
        const int plane = (idx >> 9) & 1, s = (idx >> 10) & 3, ct = (idx >> 12) & 3;
        const int n = ct * 16 + (l & 15);
        const int k = s * 32 + (l >> 4) * 8 + j;
        const float f = emb_w[k * 64 + n];
        const unsigned short hb = f2bf(f);
        wpe[idx] = plane ? f2bf(f - bfbits2f(hb)) : hb;
    } else if (b < 256) {
        const int idx = (b - 64) * 256 + t;              // [layer][g][ct2][s1][p1][l6][j3]
        const int j = idx & 7, l = (idx >> 3) & 63;
        const int plane = (idx >> 9) & 1, s = (idx >> 10) & 1, ct = (idx >> 11) & 3;
        const int g = (idx >> 13) & 1, layer = idx >> 14;
        const int n = ct * 16 + (l & 15);
        const int k = s * 32 + (l >> 4) * 8 + j;
        const float* W = g ? fc2 : fc1;
        const float f = W[(layer * 64 + k) * 64 + n];
        const unsigned short hb = f2bf(f);
        wpf[idx] = plane ? f2bf(f - bfbits2f(hb)) : hb;
    } else {
        if (b == 256 && t < NBKT) gcnt[t] = 0;
        const int g = (b - 256) * 256 + t;
        if (g > NGRAPH) return;
        if (g == NGRAPH) { goffs[NGRAPH] = N_NODES; return; }
        int lo = 0, hi = N_NODES;
        while (lo < hi) {
            const int mid = (lo + hi) >> 1;
            if (batch[mid] < g) lo = mid + 1; else hi = mid;
        }
        goffs[g] = lo;
    }
}

// ===========================================================================
// Binned CSR build. All bulk streams non-temporal; ebin packed to 4 B.
// ===========================================================================
__global__ __launch_bounds__(256) void bin_kernel(
    const int* __restrict__ src, const int* __restrict__ dst,
    int* __restrict__ gcnt, unsigned* __restrict__ ebin)
{
    __shared__ int hist[NBKT];
    __shared__ int basis[NBKT];
    const int t = threadIdx.x;
    const int base = blockIdx.x * EPB;
    if (t < NBKT) hist[t] = 0;
    __syncthreads();
    int sv[16], dv[16];
    #pragma unroll
    for (int i = 0; i < 16; i++) {
        const int e = base + t + i * 256;
        if (e < N_EDGES) {
            sv[i] = __builtin_nontemporal_load(&src[e]);
            dv[i] = __builtin_nontemporal_load(&dst[e]);
            atomicAdd(&hist[dv[i] / BRANGE], 1);
        } else { sv[i] = -1; dv[i] = -1; }
    }
    __syncthreads();
    if (t < NBKT) { basis[t] = atomicAdd(&gcnt[t], hist[t]); hist[t] = 0; }
    __syncthreads();
    #pragma unroll
    for (int i = 0; i < 16; i++) {
        if (dv[i] >= 0) {
            const int bb = dv[i] / BRANGE;
            const int dl = dv[i] - bb * BRANGE;
            const int pos = basis[bb] + atomicAdd(&hist[bb], 1);
            __builtin_nontemporal_store(
                (unsigned)sv[i] | ((unsigned)dl << 18),
                &ebin[(size_t)bb * BCAP + pos]);
        }
    }
}

// bindeg: per-bucket LDS histogram -> dense deg write.
__global__ __launch_bounds__(512) void bindeg_kernel(
    const int* __restrict__ gcnt, const unsigned* __restrict__ ebin,
    int* __restrict__ deg)
{
    __shared__ int hist[BRANGE];
    const int b = blockIdx.x, t = threadIdx.x;
    for (int i = t; i < BRANGE; i += 512) hist[i] = 0;
    __syncthreads();
    const int cnt = gcnt[b];
    const int r0 = b * BRANGE;
    const unsigned* __restrict__ eb = ebin + (size_t)b * BCAP;
    for (int i = t; i < cnt; i += 512) {
        const unsigned e = __builtin_nontemporal_load(&eb[i]);
        atomicAdd(&hist[e >> 18], 1);
    }
    __syncthreads();
    for (int i = t; i < BRANGE; i += 512)
        if (r0 + i < N_NODES) deg[r0 + i] = hist[i];
}

// binscatter: one block owns one bucket's contiguous csr region; cursors in LDS.
__global__ __launch_bounds__(512) void binscatter_kernel(
    const int* __restrict__ gcnt, const unsigned* __restrict__ ebin,
    const int* __restrict__ offs, int* __restrict__ csr_src)
{
    __shared__ int cur[BRANGE];
    const int b = blockIdx.x, t = threadIdx.x;
    const int r0 = b * BRANGE;
    const int lim = (r0 + BRANGE <= N_NODES) ? BRANGE : (N_NODES - r0);
    for (int i = t; i < lim; i += 512) cur[i] = offs[r0 + i];
    __syncthreads();
    const int cnt = gcnt[b];
    const unsigned* __restrict__ eb = ebin + (size_t)b * BCAP;
    for (int i = t; i < cnt; i += 512) {
        const unsigned e = __builtin_nontemporal_load(&eb[i]);
        const int pos = atomicAdd(&cur[e >> 18], 1);
        csr_src[pos] = (int)(e & 0x3FFFFu);
    }
}

// ===========================================================================
// Prefix scan over deg (unchanged)
// ===========================================================================
__global__ __launch_bounds__(256) void scan_sum_kernel(
    const int* __restrict__ deg, int* __restrict__ bsum)
{
    __shared__ int sd[256];
    const int b = blockIdx.x, t = threadIdx.x;
    const int base = b * SCAN_CHUNK;
    int s = 0;
    #pragma unroll
    for (int i = 0; i < SCAN_CHUNK / 256; i++) {
        const int idx = base + t + i * 256;
        s += (idx < N_NODES) ? deg[idx] : 0;
    }
    sd[t] = s; __syncthreads();
    for (int off = 128; off > 0; off >>= 1) {
        if (t < off) sd[t] += sd[t + off];
        __syncthreads();
    }
    if (t == 0) bsum[b] = sd[0];
}

__global__ __launch_bounds__(256) void scan_block_kernel(
    const int* __restrict__ bsum, int* __restrict__ boff, int* __restrict__ offs)
{
    __shared__ int sd[256];
    const int t = threadIdx.x;
    const int v = (t < NBLK_SCAN) ? bsum[t] : 0;
    sd[t] = v; __syncthreads();
    for (int off = 1; off < 256; off <<= 1) {
        const int u = (t >= off) ? sd[t - off] : 0;
        __syncthreads();
        sd[t] += u;
        __syncthreads();
    }
    if (t < NBLK_SCAN) boff[t] = sd[t] - v;
    if (t == 0) offs[N_NODES] = N_EDGES;
}

__global__ __launch_bounds__(256) void scan_scatter_kernel(
    const int* __restrict__ deg, const int* __restrict__ boff, int* __restrict__ offs)
{
    __shared__ int sd[256];
    const int b = blockIdx.x, t = threadIdx.x;
    const int base = b * SCAN_CHUNK + t * 4;
    int d0 = 0, d1 = 0, d2 = 0, d3 = 0;
    if (base + 0 < N_NODES) d0 = deg[base + 0];
    if (base + 1 < N_NODES) d1 = deg[base + 1];
    if (base + 2 < N_NODES) d2 = deg[base + 2];
    if (base + 3 < N_NODES) d3 = deg[base + 3];
    const int ts = d0 + d1 + d2 + d3;
    sd[t] = ts; __syncthreads();
    for (int off = 1; off < 256; off <<= 1) {
        const int u = (t >= off) ? sd[t - off] : 0;
        __syncthreads();
        sd[t] += u;
        __syncthreads();
    }
    const int excl = sd[t] - ts + boff[b];
    if (base + 0 < N_NODES) offs[base + 0] = excl;
    if (base + 1 < N_NODES) offs[base + 1] = excl + d0;
    if (base + 2 < N_NODES) offs[base + 2] = excl + d0 + d1;
    if (base + 3 < N_NODES) offs[base + 3] = excl + d0 + d1 + d2;
}

// ===========================================================================
// Pool: one 256-thread block per graph, no atomics, fully coalesced (NT reads).
// ===========================================================================
__global__ __launch_bounds__(256) void pool_kernel(
    const float* __restrict__ h, const int* __restrict__ goffs,
    float* __restrict__ pooled, float* __restrict__ cnt)
{
    __shared__ f32x4 red[4][16];
    const int g = blockIdx.x, t = threadIdx.x;
    const int s = goffs[g], e = goffs[g + 1];
    const int grp = t >> 4;      // node group 0..15
    const int q = t & 15;        // float4 slot within node
    f32x4 acc = {0.f, 0.f, 0.f, 0.f};
    for (int n = s + grp; n < e; n += 16) {
        const f32x4 v = __builtin_nontemporal_load(
            (const f32x4*)(h + (size_t)n * HID + q * 4));
        acc += v;
    }
    #pragma unroll
    for (int off = 16; off <= 32; off <<= 1) {
        acc[0] += __shfl_xor(acc[0], off, 64);
        acc[1] += __shfl_xor(acc[1], off, 64);
        acc[2] += __shfl_xor(acc[2], off, 64);
        acc[3] += __shfl_xor(acc[3], off, 64);
    }
    const int wv = t >> 6, lane = t & 63;
    if (lane < 16) red[wv][lane] = acc;
    __syncthreads();
    if (t < 16) {
        f32x4 a = red[0][t] + red[1][t] + red[2][t] + red[3][t];
        *(f32x4*)(pooled + (size_t)g * HID + t * 4) = a;
    }
    if (t == 0) cnt[g] = (float)(e - s);
}

// ===========================================================================
// Embed: h0 = relu(bn(x @ W + b)) via split-bf16 MFMA. x NT-read, h NT-write.
// ===========================================================================
__global__ __launch_bounds__(256) void embed_kernel(
    const float* __restrict__ x, const unsigned short* __restrict__ wpe,
    const float* __restrict__ bias,
    const float* __restrict__ bn_g, const float* __restrict__ bn_b,
    const float* __restrict__ bn_m, const float* __restrict__ bn_v,
    float* __restrict__ h)
{
    __shared__ __align__(16) float Ush[8192];                  // 32 KB union
    __shared__ float BNs[128];
    short* Abuf = (short*)Ush;
    float* Ztmp = Ush;
    const int t = threadIdx.x, lane = t & 63, w = t >> 6;
    const int base = blockIdx.x * TILE_N;

    if (t < 64) {
        const float s = bn_g[t] * rsqrtf(bn_v[t] + BN_EPS);
        BNs[t] = s;
        BNs[64 + t] = bias[t] * s + bn_b[t] - bn_m[t] * s;
    }
    // stage + hi/lo convert x tile into A-frag order (swizzled slots)
    #pragma unroll
    for (int i = 0; i < 8; i++) {
        const int idx = t + i * 256;                 // 0..2047
        const int n = idx >> 5, k4 = idx & 31;
        const f32x4 v = __builtin_nontemporal_load(
            (const f32x4*)(x + (size_t)(base + n) * IN_DIM + k4 * 4));
        uint2 hi, lo; cvt4(v, hi, lo);
        const int s = k4 >> 3, lc = (n & 15) + 16 * ((k4 >> 1) & 3);
        const int half = k4 & 1, wm = n >> 4;
        const int sl0 = ((wm * 4 + s) * 2 + 0) * 64 + lc;
        const int sl1 = ((wm * 4 + s) * 2 + 1) * 64 + lc;
        *(uint2*)&Abuf[SWZ(sl0) * 8 + half * 4] = hi;
        *(uint2*)&Abuf[SWZ(sl1) * 8 + half * 4] = lo;
    }
    __syncthreads();

    const bf16x8* A = (const bf16x8*)Abuf;
    const bf16x8* B = (const bf16x8*)wpe;
    bf16x8 ah[4], al[4];
    #pragma unroll
    for (int s = 0; s < 4; s++) {
        ah[s] = A[SWZ(((w * 4 + s) * 2 + 0) * 64 + lane)];
        al[s] = A[SWZ(((w * 4 + s) * 2 + 1) * 64 + lane)];
    }
    __syncthreads();    // all frag reads done; Ztmp may overwrite Abuf
    const int q = lane >> 4, c = lane & 15;
    #pragma unroll
    for (int ct = 0; ct < 4; ct++) {
        f32x4 acc = {0.f, 0.f, 0.f, 0.f};
        #pragma unroll
        for (int s = 0; s < 4; s++) {
            const bf16x8 bh = B[(ct << 9) + (s << 7) + lane];
            const bf16x8 bl = B[(ct << 9) + (s << 7) + 64 + lane];
            acc = MFMA16(ah[s], bh, acc);
            acc = MFMA16(ah[s], bl, acc);
            acc = MFMA16(al[s], bh, acc);
        }
        const int n = ct * 16 + c;
        const float sc = BNs[n], sh = BNs[64 + n];
        #pragma unroll
        for (int r = 0; r < 4; r++)
            Ztmp[(w * 16 + q * 4 + r) * ZS + n] = fmaxf(acc[r] * sc + sh, 0.f);
    }
    __syncthreads();
    #pragma unroll
    for (int i = 0; i < 4; i++) {
        const int idx = t + i * 256, n = idx >> 4, k4 = idx & 15;
        const f32x4 z = *(const f32x4*)(&Ztmp[n * ZS + k4 * 4]);
        __builtin_nontemporal_store(z,
            (f32x4*)(h + (size_t)(base + n) * HID + k4 * 4));
    }
}

// ===========================================================================
// Fused GIN layer. Gather loads stay CACHED; residual reads + hout writes are
// NON-TEMPORAL so the read-once/write-once streams don't evict gather rows
// from L2 (fetch-path throughput is the bottleneck).
// ===========================================================================
__global__ __launch_bounds__(256, 6) void agg_mlp_kernel(
    const float* __restrict__ hin, float* __restrict__ hout,
    const int* __restrict__ offs, const int* __restrict__ csr,
    const unsigned short* __restrict__ wp1, const unsigned short* __restrict__ wp2,
    const float* __restrict__ b1, const float* __restrict__ g1,
    const float* __restrict__ bb1, const float* __restrict__ m1, const float* __restrict__ v1,
    const float* __restrict__ b2, const float* __restrict__ g2,
    const float* __restrict__ bb2, const float* __restrict__ m2, const float* __restrict__ v2)
{
    __shared__ __align__(16) float Ush[TILE_N * ZS];           // 17408 B union
    __shared__ int   OF[TILE_N + 1];
    __shared__ int   EIDX[ECAP];                               // 4 KB
    __shared__ float BNs[256];
    short* Abuf = (short*)Ush;
    float* Ztmp = Ush;
    const int t = threadIdx.x, lane = t & 63, w = t >> 6;
    const int sub = lane >> 4, cq = lane & 15;
    const int base = blockIdx.x * TILE_N;

    if (t < 64) {
        const float sa = g1[t] * rsqrtf(v1[t] + BN_EPS);
        BNs[t] = sa; BNs[64 + t] = b1[t] * sa + bb1[t] - m1[t] * sa;
        const float sb = g2[t] * rsqrtf(v2[t] + BN_EPS);
        BNs[128 + t] = sb; BNs[192 + t] = b2[t] * sb + bb2[t] - m2[t] * sb;
    }
    if (t <= TILE_N) OF[t] = offs[base + t];
    const int segStart = offs[base];
    const int segEnd   = offs[base + TILE_N];
    for (int i = t; i < segEnd - segStart; i += 256)
        if (i < ECAP) EIDX[i] = csr[segStart + i];
    __syncthreads();

    // gather -> A-frag hi/lo writes (swizzled slots)
    // two chains (A,B) advance together: 8 independent loads per wait
    const float* __restrict__ hc = hin + cq * 4;
    #pragma unroll
    for (int pp = 0; pp < 2; pp++) {
        const int mlA = (pp * 2 + 0) * 4 + sub;
        const int mlB = (pp * 2 + 1) * 4 + sub;
        const int nlA = w * 16 + mlA, nlB = w * 16 + mlB;
        int eA = OF[nlA]; const int eA1 = OF[nlA + 1];
        int eB = OF[nlB]; const int eB1 = OF[nlB + 1];
        // clamp targets stay inside [segStart, segEnd): deg-0-safe
        const int eAm = (eA1 - 1 > segStart) ? eA1 - 1 : segStart;
        const int eBm = (eB1 - 1 > segStart) ? eB1 - 1 : segStart;
        f32x4 accA = __builtin_nontemporal_load(
            (const f32x4*)(hin + (size_t)(base + nlA) * HID + cq * 4));
        f32x4 accB = __builtin_nontemporal_load(
            (const f32x4*)(hin + (size_t)(base + nlB) * HID + cq * 4));
        while (eA < eA1 || eB < eB1) {
            int ia[4], ib[4];
            #pragma unroll
            for (int k = 0; k < 4; k++) {
                const int ea = (eA + k < eAm) ? eA + k : eAm;
                const int eb = (eB + k < eBm) ? eB + k : eBm;
                const int la = ea - segStart, lb = eb - segStart;
                ia[k] = (la < ECAP) ? EIDX[la] : csr[ea];
                ib[k] = (lb < ECAP) ? EIDX[lb] : csr[eb];
            }
            f32x4 va[4], vb[4];
            #pragma unroll
            for (int k = 0; k < 4; k++) {
                va[k] = *(const f32x4*)(hc + (size_t)ia[k] * HID);
                vb[k] = *(const f32x4*)(hc + (size_t)ib[k] * HID);
            }
            #pragma unroll
            for (int k = 0; k < 4; k++) {
                const float ma = (eA + k < eA1) ? 1.f : 0.f;
                const float mb = (eB + k < eB1) ? 1.f : 0.f;
                accA += va[k] * ma;
                accB += vb[k] * mb;
            }
            eA += 4; eB += 4;
        }
        {
            uint2 hi, lo; cvt4(accA, hi, lo);
            const int s = cq >> 3, lc = mlA + 16 * ((cq >> 1) & 3), half = cq & 1;
            const int sl0 = ((w * 2 + s) * 2 + 0) * 64 + lc;
            const int sl1 = ((w * 2 + s) * 2 + 1) * 64 + lc;
            *(uint2*)&Abuf[SWZ(sl0) * 8 + half * 4] = hi;
            *(uint2*)&Abuf[SWZ(sl1) * 8 + half * 4] = lo;
        }
        {
            uint2 hi, lo; cvt4(accB, hi, lo);
            const int s = cq >> 3, lc = mlB + 16 * ((cq >> 1) & 3), half = cq & 1;
            const int sl0 = ((w * 2 + s) * 2 + 0) * 64 + lc;
            const int sl1 = ((w * 2 + s) * 2 + 1) * 64 + lc;
            *(uint2*)&Abuf[SWZ(sl0) * 8 + half * 4] = hi;
            *(uint2*)&Abuf[SWZ(sl1) * 8 + half * 4] = lo;
        }
    }
    __syncthreads();

    const bf16x8* A = (const bf16x8*)Abuf;
    const int q = lane >> 4, c = lane & 15;

    // GEMM1
    {
        const bf16x8 a0h = A[SWZ(((w * 2 + 0) * 2 + 0) * 64 + lane)];
        const bf16x8 a0l = A[SWZ(((w * 2 + 0) * 2 + 1) * 64 + lane)];
        const bf16x8 a1h = A[SWZ(((w * 2 + 1) * 2 + 0) * 64 + lane)];
        const bf16x8 a1l = A[SWZ(((w * 2 + 1) * 2 + 1) * 64 + lane)];
        __syncthreads();    // frag reads done; Ztmp writes may alias Abuf
        const bf16x8* B = (const bf16x8*)wp1;
        #pragma unroll
        for (int ct = 0; ct < 4; ct++) {
            const bf16x8 b0h = B[(ct << 8) + lane];
            const bf16x8 b0l = B[(ct << 8) + 64 + lane];
            const bf16x8 b1h_ = B[(ct << 8) + 128 + lane];
            const bf16x8 b1l_ = B[(ct << 8) + 192 + lane];
            f32x4 acc = {0.f, 0.f, 0.f, 0.f};
            acc = MFMA16(a0h, b0h, acc);
            acc = MFMA16(a0h, b0l, acc);
            acc = MFMA16(a0l, b0h, acc);
            acc = MFMA16(a1h, b1h_, acc);
            acc = MFMA16(a1h, b1l_, acc);
            acc = MFMA16(a1l, b1h_, acc);
            const int n = ct * 16 + c;
            const float sc = BNs[n], sh = BNs[64 + n];
            #pragma unroll
            for (int r = 0; r < 4; r++)
                Ztmp[(w * 16 + q * 4 + r) * ZS + n] = fmaxf(acc[r] * sc + sh, 0.f);
        }
    }
    __syncthreads();    // Ztmp complete

    // re-split t1 into A-frags (register-staged: read all, barrier, write)
    {
        const int m = t >> 2;
        f32x4 vv[4];
        #pragma unroll
        for (int d = 0; d < 4; d++) {
            const int k4 = (t & 3) * 4 + d;
            vv[d] = *(const f32x4*)(&Ztmp[m * ZS + k4 * 4]);
        }
        __syncthreads();    // Ztmp reads done; A-frag writes may alias
        #pragma unroll
        for (int d = 0; d < 4; d++) {
            const int k4 = (t & 3) * 4 + d;
            uint2 hi, lo; cvt4(vv[d], hi, lo);
            const int s = k4 >> 3, lc = (m & 15) + 16 * ((k4 >> 1) & 3);
            const int half = k4 & 1, wm = m >> 4;
            const int sl0 = ((wm * 2 + s) * 2 + 0) * 64 + lc;
            const int sl1 = ((wm * 2 + s) * 2 + 1) * 64 + lc;
            *(uint2*)&Abuf[SWZ(sl0) * 8 + half * 4] = hi;
            *(uint2*)&Abuf[SWZ(sl1) * 8 + half * 4] = lo;
        }
    }
    __syncthreads();

    // GEMM2
    {
        const bf16x8 a0h = A[SWZ(((w * 2 + 0) * 2 + 0) * 64 + lane)];
        const bf16x8 a0l = A[SWZ(((w * 2 + 0) * 2 + 1) * 64 + lane)];
        const bf16x8 a1h = A[SWZ(((w * 2 + 1) * 2 + 0) * 64 + lane)];
        const bf16x8 a1l = A[SWZ(((w * 2 + 1) * 2 + 1) * 64 + lane)];
        __syncthreads();    // frag reads done; Ztmp writes may alias Abuf
        const bf16x8* B = (const bf16x8*)wp2;
        #pragma unroll
        for (int ct = 0; ct < 4; ct++) {
            const bf16x8 b0h = B[(ct << 8) + lane];
            const bf16x8 b0l = B[(ct << 8) + 64 + lane];
            const bf16x8 b1h_ = B[(ct << 8) + 128 + lane];
            const bf16x8 b1l_ = B[(ct << 8) + 192 + lane];
            f32x4 acc = {0.f, 0.f, 0.f, 0.f};
            acc = MFMA16(a0h, b0h, acc);
            acc = MFMA16(a0h, b0l, acc);
            acc = MFMA16(a0l, b0h, acc);
            acc = MFMA16(a1h, b1h_, acc);
            acc = MFMA16(a1h, b1l_, acc);
            acc = MFMA16(a1l, b1h_, acc);
            const int n = ct * 16 + c;
            const float sc = BNs[128 + n], sh = BNs[192 + n];
            #pragma unroll
            for (int r = 0; r < 4; r++)
                Ztmp[(w * 16 + q * 4 + r) * ZS + n] = fmaxf(acc[r] * sc + sh, 0.f);
        }
    }
    __syncthreads();

    #pragma unroll
    for (int i = 0; i < 4; i++) {
        const int idx = t + i * 256, n = idx >> 4, k4 = idx & 15;
        const f32x4 z = *(const f32x4*)(&Ztmp[n * ZS + k4 * 4]);
        __builtin_nontemporal_store(z,
            (f32x4*)(hout + (size_t)(base + n) * HID + k4 * 4));
    }
}

// ===========================================================================
// Classifier (unchanged)
// ===========================================================================
__global__ __launch_bounds__(64) void cls_kernel(
    const float* __restrict__ pooled, const float* __restrict__ cnt,
    const float* __restrict__ w1, const float* __restrict__ b1,
    const float* __restrict__ w2, const float* __restrict__ b2,
    float* __restrict__ out)
{
    const int g = blockIdx.x;
    const int lane = threadIdx.x;
    const float c = cnt[g];
    const float p = pooled[(size_t)g * HID + lane] / fmaxf(c, 1.f);
    float acc = (lane < 32) ? b1[lane] : 0.f;
    #pragma unroll
    for (int k = 0; k < 64; k++) {
        const float pk = __shfl(p, k, 64);
        if (lane < 32) acc += pk * w1[k * 32 + lane];
    }
    const float hmid = fmaxf(acc, 0.f);
    float acc2 = (lane < NCLS) ? b2[lane] : 0.f;
    #pragma unroll
    for (int k = 0; k < 32; k++) {
        const float hk = __shfl(hmid, k, 64);
        if (lane < NCLS) acc2 += hk * w2[k * NCLS + lane];
    }
    if (lane < NCLS) out[(size_t)g * NCLS + lane] = acc2;
}

// ===========================================================================
extern "C" void kernel_launch(void* const* d_in, const int* in_sizes, int n_in,
                              void* d_out, int out_size, void* d_ws, size_t ws_size,
                              hipStream_t stream) {
    const float* x     = (const float*)d_in[0];
    const int*   ei    = (const int*)d_in[1];
    const int*   batch = (const int*)d_in[2];
    const float* emb_w = (const float*)d_in[3];
    const float* emb_b = (const float*)d_in[4];
    const float* ibn_g = (const float*)d_in[5];
    const float* ibn_b = (const float*)d_in[6];
    const float* ibn_m = (const float*)d_in[7];
    const float* ibn_v = (const float*)d_in[8];
    const float* fc1_w = (const float*)d_in[9];
    const float* fc1_b = (const float*)d_in[10];
    const float* mbn_g = (const float*)d_in[11];
    const float* mbn_b = (const float*)d_in[12];
    const float* mbn_m = (const float*)d_in[13];
    const float* mbn_v = (const float*)d_in[14];
    const float* fc2_w = (const float*)d_in[15];
    const float* fc2_b = (const float*)d_in[16];
    const float* obn_g = (const float*)d_in[17];
    const float* obn_b = (const float*)d_in[18];
    const float* obn_m = (const float*)d_in[19];
    const float* obn_v = (const float*)d_in[20];
    const float* cls1w = (const float*)d_in[21];
    const float* cls1b = (const float*)d_in[22];
    const float* cls2w = (const float*)d_in[23];
    const float* cls2b = (const float*)d_in[24];

    float* h0     = (float*)d_ws;
    float* h1     = h0 + (size_t)N_NODES * HID;
    float* pooled = h1 + (size_t)N_NODES * HID;
    float* cnt    = pooled + NGRAPH * HID;
    int*   deg    = (int*)(cnt + NGRAPH);
    int*   offs   = deg + N_NODES;
    int*   bsum   = offs + (N_NODES + 1);
    int*   boff   = bsum + NBLK_SCAN;
    int*   csr    = boff + NBLK_SCAN;
    unsigned short* wpe = (unsigned short*)(csr + N_EDGES);   // 16384
    unsigned short* wpf = wpe + 16384;                        // 49152
    int*   goffs  = (int*)(wpf + 49152);                      // NGRAPH+1
    int*   gcnt   = goffs + (NGRAPH + 1);                     // NBKT
    // ebin (packed u32) reuses h0 space: CSR build completes before embed
    // writes h0. 128*12288*4 B = 6.3 MB << 51.2 MB.
    unsigned* ebin = (unsigned*)h0;

    const int* src = ei;
    const int* dst = ei + N_EDGES;

    // weight prep + graph offsets + gcnt zero (fused)
    setup_kernel<<<261, 256, 0, stream>>>(emb_w, wpe, fc1_w, fc2_w, wpf,
                                          batch, goffs, gcnt);

    // binned CSR build
    bin_kernel<<<NB_BIN, 256, 0, stream>>>(src, dst, gcnt, ebin);
    bindeg_kernel<<<NBKT, 512, 0, stream>>>(gcnt, ebin, deg);
    scan_sum_kernel<<<NBLK_SCAN, 256, 0, stream>>>(deg, bsum);
    scan_block_kernel<<<1, 256, 0, stream>>>(bsum, boff, offs);
    scan_scatter_kernel<<<NBLK_SCAN, 256, 0, stream>>>(deg, boff, offs);
    binscatter_kernel<<<NBKT, 512, 0, stream>>>(gcnt, ebin, offs, csr);

    // network
    const int gemm_blocks = N_NODES / TILE_N;   // 3125
    embed_kernel<<<gemm_blocks, 256, 0, stream>>>(x, wpe, emb_b,
                                                  ibn_g, ibn_b, ibn_m, ibn_v, h0);

    const float* hin = h0;
    float* hout = h1;
    for (int i = 0; i < 3; i++) {
        agg_mlp_kernel<<<gemm_blocks, 256, 0, stream>>>(
            hin, hout, offs, csr,
            wpf + (size_t)(i * 2 + 0) * 8192, wpf + (size_t)(i * 2 + 1) * 8192,
            fc1_b + i * HID, mbn_g + i * HID, mbn_b + i * HID, mbn_m + i * HID, mbn_v + i * HID,
            fc2_b + i * HID, obn_g + i * HID, obn_b + i * HID, obn_m + i * HID, obn_v + i * HID);
        const float* tmp = hin; hin = hout; hout = (float*)tmp;
    }

    // pool: one block per graph, no atomics
    pool_kernel<<<NGRAPH, 256, 0, stream>>>(h1, goffs, pooled, cnt);

    cls_kernel<<<NGRAPH, 64, 0, stream>>>(pooled, cnt, cls1w, cls1b, cls2w, cls2b,
                                          (float*)d_out);
}

// Round 6
// 496.184 us; speedup vs baseline: 1.0307x; 1.0307x over previous
//
#include <hip/hip_runtime.h>
#include <hip/hip_bf16.h>

#define N_NODES 200000
#define N_EDGES 1200000
#define IN_DIM  128
#define HID     64
#define NGRAPH  1024
#define NCLS    6
#define BN_EPS  1e-5f

#define TILE_N   64
#define ZS       68          // Ztmp row stride (floats); 272B = 17 banks shift, 2-way max
#define ECAP     1024

#define SCAN_CHUNK 1024
#define NBLK_SCAN ((N_NODES + SCAN_CHUNK - 1) / SCAN_CHUNK)   // 196

// ---- binned CSR build ----
#define NBKT   128           // dst-range buckets
#define BRANGE 1568          // nodes per bucket (128*1568 = 200704 >= N)
#define BCAP   12288         // per-bucket edge capacity (mean 9408, sigma ~97)
#define EPB    4096          // edges per bin_kernel block
#define NB_BIN ((N_EDGES + EPB - 1) / EPB)   // 293
// packed ebin entry: src (18b) | dstLocal (11b) << 18

// 16B-slot XOR swizzle for A-frag LDS
#define SWZ(s) ((s) ^ (((s) >> 4) & 3))

typedef short bf16x8 __attribute__((ext_vector_type(8)));
typedef float f32x4  __attribute__((ext_vector_type(4)));
#define MFMA16(a,b,c) __builtin_amdgcn_mfma_f32_16x16x32_bf16((a),(b),(c),0,0,0)

template<bool V> struct BoolC { static constexpr bool value = V; };

__device__ __forceinline__ unsigned short f2bf(float f) {
    union { __hip_bfloat16 h; unsigned short u; } v; v.h = __float2bfloat16(f); return v.u;
}
__device__ __forceinline__ float bfbits2f(unsigned short u) {
    union { unsigned int i; float f; } v; v.i = ((unsigned int)u) << 16; return v.f;
}
// f32x4 -> (hi bf16x4, lo bf16x4) packed as uint2 each
__device__ __forceinline__ void cvt4(const f32x4& x, uint2& hi, uint2& lo) {
    const unsigned short h0 = f2bf(x[0]), h1 = f2bf(x[1]), h2 = f2bf(x[2]), h3 = f2bf(x[3]);
    hi.x = (unsigned)h0 | ((unsigned)h1 << 16);
    hi.y = (unsigned)h2 | ((unsigned)h3 << 16);
    const unsigned short l0 = f2bf(x[0] - bfbits2f(h0)), l1 = f2bf(x[1] - bfbits2f(h1));
    const unsigned short l2 = f2bf(x[2] - bfbits2f(h2)), l3 = f2bf(x[3] - bfbits2f(h3));
    lo.x = (unsigned)l0 | ((unsigned)l1 << 16);
    lo.y = (unsigned)l2 | ((unsigned)l3 << 16);
}

// ===========================================================================
// Setup kernel: prep_emb (blocks 0..63) + prep_fc (64..255) + graph_offs /
// gcnt zero (256..260). Weight B-frag packing, bf16 hi/lo planes.
// ===========================================================================
__global__ __launch_bounds__(256) void setup_kernel(
    const float* __restrict__ emb_w, unsigned short* __restrict__ wpe,
    const float* __restrict__ fc1, const float* __restrict__ fc2,
    unsigned short* __restrict__ wpf,
    const int* __restrict__ batch, int* __restrict__ goffs,
    int* __restrict__ gcnt)
{
    const int b = blockIdx.x, t = threadIdx.x;
    if (b < 64) {
        const int idx = b * 256 + t;                     // [ct2][s2][p1][l6][j3]
        const int j = idx & 7, l = (idx >> 3) & 63;
        const int plane = (idx >> 9) & 1, s = (idx >> 10) & 3, ct = (idx >> 12) & 3;
        const int n = ct * 16 + (l & 15);
        const int k = s * 32 + (l >> 4) * 8 + j;
        const float f = emb_w[k * 64 + n];
        const unsigned short hb = f2bf(f);
        wpe[idx] = plane ? f2bf(f - bfbits2f(hb)) : hb;
    } else if (b < 256) {
        const int idx = (b - 64) * 256 + t;              // [layer][g][ct2][s1][p1][l6][j3]
        const int j = idx & 7, l = (idx >> 3) & 63;
        const int plane = (idx >> 9) & 1, s = (idx >> 10) & 1, ct = (idx >> 11) & 3;
        const int g = (idx >> 13) & 1, layer = idx >> 14;
        const int n = ct * 16 + (l & 15);
        const int k = s * 32 + (l >> 4) * 8 + j;
        const float* W = g ? fc2 : fc1;
        const float f = W[(layer * 64 + k) * 64 + n];
        const unsigned short hb = f2bf(f);
        wpf[idx] = plane ? f2bf(f - bfbits2f(hb)) : hb;
    } else {
        if (b == 256 && t < NBKT) gcnt[t] = 0;
        const int g = (b - 256) * 256 + t;
        if (g > NGRAPH) return;
        if (g == NGRAPH) { goffs[NGRAPH] = N_NODES; return; }
        int lo = 0, hi = N_NODES;
        while (lo < hi) {
            const int mid = (lo + hi) >> 1;
            if (batch[mid] < g) lo = mid + 1; else hi = mid;
        }
        goffs[g] = lo;
    }
}

// ===========================================================================
// Binned CSR build. Bulk streams NT (truly read/write-once); ebin packed 4 B.
// ===========================================================================
__global__ __launch_bounds__(256) void bin_kernel(
    const int* __restrict__ src, const int* __restrict__ dst,
    int* __restrict__ gcnt, unsigned* __restrict__ ebin)
{
    __shared__ int hist[NBKT];
    __shared__ int basis[NBKT];
    const int t = threadIdx.x;
    const int base = blockIdx.x * EPB;
    if (t < NBKT) hist[t] = 0;
    __syncthreads();
    int sv[16], dv[16];
    #pragma unroll
    for (int i = 0; i < 16; i++) {
        const int e = base + t + i * 256;
        if (e < N_EDGES) {
            sv[i] = __builtin_nontemporal_load(&src[e]);
            dv[i] = __builtin_nontemporal_load(&dst[e]);
            atomicAdd(&hist[dv[i] / BRANGE], 1);
        } else { sv[i] = -1; dv[i] = -1; }
    }
    __syncthreads();
    if (t < NBKT) { basis[t] = atomicAdd(&gcnt[t], hist[t]); hist[t] = 0; }
    __syncthreads();
    #pragma unroll
    for (int i = 0; i < 16; i++) {
        if (dv[i] >= 0) {
            const int bb = dv[i] / BRANGE;
            const int dl = dv[i] - bb * BRANGE;
            const int pos = basis[bb] + atomicAdd(&hist[bb], 1);
            __builtin_nontemporal_store(
                (unsigned)sv[i] | ((unsigned)dl << 18),
                &ebin[(size_t)bb * BCAP + pos]);
        }
    }
}

// bindeg: per-bucket LDS histogram -> dense deg write.
__global__ __launch_bounds__(512) void bindeg_kernel(
    const int* __restrict__ gcnt, const unsigned* __restrict__ ebin,
    int* __restrict__ deg)
{
    __shared__ int hist[BRANGE];
    const int b = blockIdx.x, t = threadIdx.x;
    for (int i = t; i < BRANGE; i += 512) hist[i] = 0;
    __syncthreads();
    const int cnt = gcnt[b];
    const int r0 = b * BRANGE;
    const unsigned* __restrict__ eb = ebin + (size_t)b * BCAP;
    for (int i = t; i < cnt; i += 512) {
        const unsigned e = __builtin_nontemporal_load(&eb[i]);
        atomicAdd(&hist[e >> 18], 1);
    }
    __syncthreads();
    for (int i = t; i < BRANGE; i += 512)
        if (r0 + i < N_NODES) deg[r0 + i] = hist[i];
}

// binscatter: one block owns one bucket's contiguous csr region; cursors in LDS.
__global__ __launch_bounds__(512) void binscatter_kernel(
    const int* __restrict__ gcnt, const unsigned* __restrict__ ebin,
    const int* __restrict__ offs, int* __restrict__ csr_src)
{
    __shared__ int cur[BRANGE];
    const int b = blockIdx.x, t = threadIdx.x;
    const int r0 = b * BRANGE;
    const int lim = (r0 + BRANGE <= N_NODES) ? BRANGE : (N_NODES - r0);
    for (int i = t; i < lim; i += 512) cur[i] = offs[r0 + i];
    __syncthreads();
    const int cnt = gcnt[b];
    const unsigned* __restrict__ eb = ebin + (size_t)b * BCAP;
    for (int i = t; i < cnt; i += 512) {
        const unsigned e = __builtin_nontemporal_load(&eb[i]);
        const int pos = atomicAdd(&cur[e >> 18], 1);
        csr_src[pos] = (int)(e & 0x3FFFFu);
    }
}

// ===========================================================================
// Prefix scan over deg (unchanged)
// ===========================================================================
__global__ __launch_bounds__(256) void scan_sum_kernel(
    const int* __restrict__ deg, int* __restrict__ bsum)
{
    __shared__ int sd[256];
    const int b = blockIdx.x, t = threadIdx.x;
    const int base = b * SCAN_CHUNK;
    int s = 0;
    #pragma unroll
    for (int i = 0; i < SCAN_CHUNK / 256; i++) {
        const int idx = base + t + i * 256;
        s += (idx < N_NODES) ? deg[idx] : 0;
    }
    sd[t] = s; __syncthreads();
    for (int off = 128; off > 0; off >>= 1) {
        if (t < off) sd[t] += sd[t + off];
        __syncthreads();
    }
    if (t == 0) bsum[b] = sd[0];
}

__global__ __launch_bounds__(256) void scan_block_kernel(
    const int* __restrict__ bsum, int* __restrict__ boff, int* __restrict__ offs)
{
    __shared__ int sd[256];
    const int t = threadIdx.x;
    const int v = (t < NBLK_SCAN) ? bsum[t] : 0;
    sd[t] = v; __syncthreads();
    for (int off = 1; off < 256; off <<= 1) {
        const int u = (t >= off) ? sd[t - off] : 0;
        __syncthreads();
        sd[t] += u;
        __syncthreads();
    }
    if (t < NBLK_SCAN) boff[t] = sd[t] - v;
    if (t == 0) offs[N_NODES] = N_EDGES;
}

__global__ __launch_bounds__(256) void scan_scatter_kernel(
    const int* __restrict__ deg, const int* __restrict__ boff, int* __restrict__ offs)
{
    __shared__ int sd[256];
    const int b = blockIdx.x, t = threadIdx.x;
    const int base = b * SCAN_CHUNK + t * 4;
    int d0 = 0, d1 = 0, d2 = 0, d3 = 0;
    if (base + 0 < N_NODES) d0 = deg[base + 0];
    if (base + 1 < N_NODES) d1 = deg[base + 1];
    if (base + 2 < N_NODES) d2 = deg[base + 2];
    if (base + 3 < N_NODES) d3 = deg[base + 3];
    const int ts = d0 + d1 + d2 + d3;
    sd[t] = ts; __syncthreads();
    for (int off = 1; off < 256; off <<= 1) {
        const int u = (t >= off) ? sd[t - off] : 0;
        __syncthreads();
        sd[t] += u;
        __syncthreads();
    }
    const int excl = sd[t] - ts + boff[b];
    if (base + 0 < N_NODES) offs[base + 0] = excl;
    if (base + 1 < N_NODES) offs[base + 1] = excl + d0;
    if (base + 2 < N_NODES) offs[base + 2] = excl + d0 + d1;
    if (base + 3 < N_NODES) offs[base + 3] = excl + d0 + d1 + d2;
}

// ===========================================================================
// Pool: one 256-thread block per graph, no atomics, fully coalesced.
// NT reads OK here: h1's final consumer.
// ===========================================================================
__global__ __launch_bounds__(256) void pool_kernel(
    const float* __restrict__ h, const int* __restrict__ goffs,
    float* __restrict__ pooled, float* __restrict__ cnt)
{
    __shared__ f32x4 red[4][16];
    const int g = blockIdx.x, t = threadIdx.x;
    const int s = goffs[g], e = goffs[g + 1];
    const int grp = t >> 4;      // node group 0..15
    const int q = t & 15;        // float4 slot within node
    f32x4 acc = {0.f, 0.f, 0.f, 0.f};
    for (int n = s + grp; n < e; n += 16) {
        const f32x4 v = __builtin_nontemporal_load(
            (const f32x4*)(h + (size_t)n * HID + q * 4));
        acc += v;
    }
    #pragma unroll
    for (int off = 16; off <= 32; off <<= 1) {
        acc[0] += __shfl_xor(acc[0], off, 64);
        acc[1] += __shfl_xor(acc[1], off, 64);
        acc[2] += __shfl_xor(acc[2], off, 64);
        acc[3] += __shfl_xor(acc[3], off, 64);
    }
    const int wv = t >> 6, lane = t & 63;
    if (lane < 16) red[wv][lane] = acc;
    __syncthreads();
    if (t < 16) {
        f32x4 a = red[0][t] + red[1][t] + red[2][t] + red[3][t];
        *(f32x4*)(pooled + (size_t)g * HID + t * 4) = a;
    }
    if (t == 0) cnt[g] = (float)(e - s);
}

// ===========================================================================
// Embed: h0 = relu(bn(x @ W + b)) via split-bf16 MFMA.
// x NT-read (true stream); h0 store NORMAL (layer-1 gather prefill).
// ===========================================================================
__global__ __launch_bounds__(256) void embed_kernel(
    const float* __restrict__ x, const unsigned short* __restrict__ wpe,
    const float* __restrict__ bias,
    const float* __restrict__ bn_g, const float* __restrict__ bn_b,
    const float* __restrict__ bn_m, const float* __restrict__ bn_v,
    float* __restrict__ h)
{
    __shared__ __align__(16) float Ush[8192];                  // 32 KB union
    __shared__ float BNs[128];
    short* Abuf = (short*)Ush;
    float* Ztmp = Ush;
    const int t = threadIdx.x, lane = t & 63, w = t >> 6;
    const int base = blockIdx.x * TILE_N;

    if (t < 64) {
        const float s = bn_g[t] * rsqrtf(bn_v[t] + BN_EPS);
        BNs[t] = s;
        BNs[64 + t] = bias[t] * s + bn_b[t] - bn_m[t] * s;
    }
    // stage + hi/lo convert x tile into A-frag order (swizzled slots)
    #pragma unroll
    for (int i = 0; i < 8; i++) {
        const int idx = t + i * 256;                 // 0..2047
        const int n = idx >> 5, k4 = idx & 31;
        const f32x4 v = __builtin_nontemporal_load(
            (const f32x4*)(x + (size_t)(base + n) * IN_DIM + k4 * 4));
        uint2 hi, lo; cvt4(v, hi, lo);
        const int s = k4 >> 3, lc = (n & 15) + 16 * ((k4 >> 1) & 3);
        const int half = k4 & 1, wm = n >> 4;
        const int sl0 = ((wm * 4 + s) * 2 + 0) * 64 + lc;
        const int sl1 = ((wm * 4 + s) * 2 + 1) * 64 + lc;
        *(uint2*)&Abuf[SWZ(sl0) * 8 + half * 4] = hi;
        *(uint2*)&Abuf[SWZ(sl1) * 8 + half * 4] = lo;
    }
    __syncthreads();

    const bf16x8* A = (const bf16x8*)Abuf;
    const bf16x8* B = (const bf16x8*)wpe;
    bf16x8 ah[4], al[4];
    #pragma unroll
    for (int s = 0; s < 4; s++) {
        ah[s] = A[SWZ(((w * 4 + s) * 2 + 0) * 64 + lane)];
        al[s] = A[SWZ(((w * 4 + s) * 2 + 1) * 64 + lane)];
    }
    __syncthreads();    // all frag reads done; Ztmp may overwrite Abuf
    const int q = lane >> 4, c = lane & 15;
    #pragma unroll
    for (int ct = 0; ct < 4; ct++) {
        f32x4 acc = {0.f, 0.f, 0.f, 0.f};
        #pragma unroll
        for (int s = 0; s < 4; s++) {
            const bf16x8 bh = B[(ct << 9) + (s << 7) + lane];
            const bf16x8 bl = B[(ct << 9) + (s << 7) + 64 + lane];
            acc = MFMA16(ah[s], bh, acc);
            acc = MFMA16(ah[s], bl, acc);
            acc = MFMA16(al[s], bh, acc);
        }
        const int n = ct * 16 + c;
        const float sc = BNs[n], sh = BNs[64 + n];
        #pragma unroll
        for (int r = 0; r < 4; r++)
            Ztmp[(w * 16 + q * 4 + r) * ZS + n] = fmaxf(acc[r] * sc + sh, 0.f);
    }
    __syncthreads();
    #pragma unroll
    for (int i = 0; i < 4; i++) {
        const int idx = t + i * 256, n = idx >> 4, k4 = idx & 15;
        *(f32x4*)(h + (size_t)(base + n) * HID + k4 * 4) =
            *(const f32x4*)(&Ztmp[n * ZS + k4 * 4]);
    }
}

// ===========================================================================
// Fused GIN layer. All h accesses CACHED (h rows carry gather reuse — r4's
// NT experiment regressed 15%). Tile-uniform allLds branch removes the
// per-edge predicated csr[] global load (compiler can't skip it in the
// ternary; it was ~5 MB FETCH + 8 wasted load-issues per iteration).
// ===========================================================================
__global__ __launch_bounds__(256, 7) void agg_mlp_kernel(
    const float* __restrict__ hin, float* __restrict__ hout,
    const int* __restrict__ offs, const int* __restrict__ csr,
    const unsigned short* __restrict__ wp1, const unsigned short* __restrict__ wp2,
    const float* __restrict__ b1, const float* __restrict__ g1,
    const float* __restrict__ bb1, const float* __restrict__ m1, const float* __restrict__ v1,
    const float* __restrict__ b2, const float* __restrict__ g2,
    const float* __restrict__ bb2, const float* __restrict__ m2, const float* __restrict__ v2)
{
    __shared__ __align__(16) float Ush[TILE_N * ZS];           // 17408 B union
    __shared__ int   OF[TILE_N + 1];
    __shared__ int   EIDX[ECAP];                               // 4 KB
    __shared__ float BNs[256];
    short* Abuf = (short*)Ush;
    float* Ztmp = Ush;
    const int t = threadIdx.x, lane = t & 63, w = t >> 6;
    const int sub = lane >> 4, cq = lane & 15;
    const int base = blockIdx.x * TILE_N;

    if (t < 64) {
        const float sa = g1[t] * rsqrtf(v1[t] + BN_EPS);
        BNs[t] = sa; BNs[64 + t] = b1[t] * sa + bb1[t] - m1[t] * sa;
        const float sb = g2[t] * rsqrtf(v2[t] + BN_EPS);
        BNs[128 + t] = sb; BNs[192 + t] = b2[t] * sb + bb2[t] - m2[t] * sb;
    }
    if (t <= TILE_N) OF[t] = offs[base + t];
    const int segStart = offs[base];
    const int segEnd   = offs[base + TILE_N];
    for (int i = t; i < segEnd - segStart; i += 256)
        if (i < ECAP) EIDX[i] = csr[segStart + i];
    __syncthreads();

    // gather -> A-frag hi/lo writes (swizzled slots)
    // two chains (A,B) advance together: 8 independent loads per wait
    const float* __restrict__ hc = hin + cq * 4;
    const bool allLds = (segEnd - segStart) <= ECAP;   // true for ~all tiles

    auto gather_pass = [&](auto ldsTag) {
        constexpr bool LDSONLY = decltype(ldsTag)::value;
        #pragma unroll
        for (int pp = 0; pp < 2; pp++) {
            const int mlA = (pp * 2 + 0) * 4 + sub;
            const int mlB = (pp * 2 + 1) * 4 + sub;
            const int nlA = w * 16 + mlA, nlB = w * 16 + mlB;
            int eA = OF[nlA]; const int eA1 = OF[nlA + 1];
            int eB = OF[nlB]; const int eB1 = OF[nlB + 1];
            // clamp targets stay inside [segStart, segEnd): deg-0-safe
            const int eAm = (eA1 - 1 > segStart) ? eA1 - 1 : segStart;
            const int eBm = (eB1 - 1 > segStart) ? eB1 - 1 : segStart;
            f32x4 accA = *(const f32x4*)(hin + (size_t)(base + nlA) * HID + cq * 4);
            f32x4 accB = *(const f32x4*)(hin + (size_t)(base + nlB) * HID + cq * 4);
            while (eA < eA1 || eB < eB1) {
                int ia[4], ib[4];
                #pragma unroll
                for (int k = 0; k < 4; k++) {
                    const int ea = (eA + k < eAm) ? eA + k : eAm;
                    const int eb = (eB + k < eBm) ? eB + k : eBm;
                    const int la = ea - segStart, lb = eb - segStart;
                    if (LDSONLY) {
                        ia[k] = EIDX[la];
                        ib[k] = EIDX[lb];
                    } else {
                        ia[k] = (la < ECAP) ? EIDX[la] : csr[ea];
                        ib[k] = (lb < ECAP) ? EIDX[lb] : csr[eb];
                    }
                }
                f32x4 va[4], vb[4];
                #pragma unroll
                for (int k = 0; k < 4; k++) {
                    va[k] = *(const f32x4*)(hc + (size_t)ia[k] * HID);
                    vb[k] = *(const f32x4*)(hc + (size_t)ib[k] * HID);
                }
                #pragma unroll
                for (int k = 0; k < 4; k++) {
                    const float ma = (eA + k < eA1) ? 1.f : 0.f;
                    const float mb = (eB + k < eB1) ? 1.f : 0.f;
                    accA += va[k] * ma;
                    accB += vb[k] * mb;
                }
                eA += 4; eB += 4;
            }
            {
                uint2 hi, lo; cvt4(accA, hi, lo);
                const int s = cq >> 3, lc = mlA + 16 * ((cq >> 1) & 3), half = cq & 1;
                const int sl0 = ((w * 2 + s) * 2 + 0) * 64 + lc;
                const int sl1 = ((w * 2 + s) * 2 + 1) * 64 + lc;
                *(uint2*)&Abuf[SWZ(sl0) * 8 + half * 4] = hi;
                *(uint2*)&Abuf[SWZ(sl1) * 8 + half * 4] = lo;
            }
            {
                uint2 hi, lo; cvt4(accB, hi, lo);
                const int s = cq >> 3, lc = mlB + 16 * ((cq >> 1) & 3), half = cq & 1;
                const int sl0 = ((w * 2 + s) * 2 + 0) * 64 + lc;
                const int sl1 = ((w * 2 + s) * 2 + 1) * 64 + lc;
                *(uint2*)&Abuf[SWZ(sl0) * 8 + half * 4] = hi;
                *(uint2*)&Abuf[SWZ(sl1) * 8 + half * 4] = lo;
            }
        }
    };
    if (allLds) gather_pass(BoolC<true>{});
    else        gather_pass(BoolC<false>{});
    __syncthreads();

    const bf16x8* A = (const bf16x8*)Abuf;
    const int q = lane >> 4, c = lane & 15;

    // GEMM1
    {
        const bf16x8 a0h = A[SWZ(((w * 2 + 0) * 2 + 0) * 64 + lane)];
        const bf16x8 a0l = A[SWZ(((w * 2 + 0) * 2 + 1) * 64 + lane)];
        const bf16x8 a1h = A[SWZ(((w * 2 + 1) * 2 + 0) * 64 + lane)];
        const bf16x8 a1l = A[SWZ(((w * 2 + 1) * 2 + 1) * 64 + lane)];
        __syncthreads();    // frag reads done; Ztmp writes may alias Abuf
        const bf16x8* B = (const bf16x8*)wp1;
        #pragma unroll
        for (int ct = 0; ct < 4; ct++) {
            const bf16x8 b0h = B[(ct << 8) + lane];
            const bf16x8 b0l = B[(ct << 8) + 64 + lane];
            const bf16x8 b1h_ = B[(ct << 8) + 128 + lane];
            const bf16x8 b1l_ = B[(ct << 8) + 192 + lane];
            f32x4 acc = {0.f, 0.f, 0.f, 0.f};
            acc = MFMA16(a0h, b0h, acc);
            acc = MFMA16(a0h, b0l, acc);
            acc = MFMA16(a0l, b0h, acc);
            acc = MFMA16(a1h, b1h_, acc);
            acc = MFMA16(a1h, b1l_, acc);
            acc = MFMA16(a1l, b1h_, acc);
            const int n = ct * 16 + c;
            const float sc = BNs[n], sh = BNs[64 + n];
            #pragma unroll
            for (int r = 0; r < 4; r++)
                Ztmp[(w * 16 + q * 4 + r) * ZS + n] = fmaxf(acc[r] * sc + sh, 0.f);
        }
    }
    __syncthreads();    // Ztmp complete

    // re-split t1 into A-frags (register-staged: read all, barrier, write)
    {
        const int m = t >> 2;
        f32x4 vv[4];
        #pragma unroll
        for (int d = 0; d < 4; d++) {
            const int k4 = (t & 3) * 4 + d;
            vv[d] = *(const f32x4*)(&Ztmp[m * ZS + k4 * 4]);
        }
        __syncthreads();    // Ztmp reads done; A-frag writes may alias
        #pragma unroll
        for (int d = 0; d < 4; d++) {
            const int k4 = (t & 3) * 4 + d;
            uint2 hi, lo; cvt4(vv[d], hi, lo);
            const int s = k4 >> 3, lc = (m & 15) + 16 * ((k4 >> 1) & 3);
            const int half = k4 & 1, wm = m >> 4;
            const int sl0 = ((wm * 2 + s) * 2 + 0) * 64 + lc;
            const int sl1 = ((wm * 2 + s) * 2 + 1) * 64 + lc;
            *(uint2*)&Abuf[SWZ(sl0) * 8 + half * 4] = hi;
            *(uint2*)&Abuf[SWZ(sl1) * 8 + half * 4] = lo;
        }
    }
    __syncthreads();

    // GEMM2
    {
        const bf16x8 a0h = A[SWZ(((w * 2 + 0) * 2 + 0) * 64 + lane)];
        const bf16x8 a0l = A[SWZ(((w * 2 + 0) * 2 + 1) * 64 + lane)];
        const bf16x8 a1h = A[SWZ(((w * 2 + 1) * 2 + 0) * 64 + lane)];
        const bf16x8 a1l = A[SWZ(((w * 2 + 1) * 2 + 1) * 64 + lane)];
        __syncthreads();    // frag reads done; Ztmp writes may alias Abuf
        const bf16x8* B = (const bf16x8*)wp2;
        #pragma unroll
        for (int ct = 0; ct < 4; ct++) {
            const bf16x8 b0h = B[(ct << 8) + lane];
            const bf16x8 b0l = B[(ct << 8) + 64 + lane];
            const bf16x8 b1h_ = B[(ct << 8) + 128 + lane];
            const bf16x8 b1l_ = B[(ct << 8) + 192 + lane];
            f32x4 acc = {0.f, 0.f, 0.f, 0.f};
            acc = MFMA16(a0h, b0h, acc);
            acc = MFMA16(a0h, b0l, acc);
            acc = MFMA16(a0l, b0h, acc);
            acc = MFMA16(a1h, b1h_, acc);
            acc = MFMA16(a1h, b1l_, acc);
            acc = MFMA16(a1l, b1h_, acc);
            const int n = ct * 16 + c;
            const float sc = BNs[128 + n], sh = BNs[192 + n];
            #pragma unroll
            for (int r = 0; r < 4; r++)
                Ztmp[(w * 16 + q * 4 + r) * ZS + n] = fmaxf(acc[r] * sc + sh, 0.f);
        }
    }
    __syncthreads();

    #pragma unroll
    for (int i = 0; i < 4; i++) {
        const int idx = t + i * 256, n = idx >> 4, k4 = idx & 15;
        *(f32x4*)(hout + (size_t)(base + n) * HID + k4 * 4) =
            *(const f32x4*)(&Ztmp[n * ZS + k4 * 4]);
    }
}

// ===========================================================================
// Classifier (unchanged)
// ===========================================================================
__global__ __launch_bounds__(64) void cls_kernel(
    const float* __restrict__ pooled, const float* __restrict__ cnt,
    const float* __restrict__ w1, const float* __restrict__ b1,
    const float* __restrict__ w2, const float* __restrict__ b2,
    float* __restrict__ out)
{
    const int g = blockIdx.x;
    const int lane = threadIdx.x;
    const float c = cnt[g];
    const float p = pooled[(size_t)g * HID + lane] / fmaxf(c, 1.f);
    float acc = (lane < 32) ? b1[lane] : 0.f;
    #pragma unroll
    for (int k = 0; k < 64; k++) {
        const float pk = __shfl(p, k, 64);
        if (lane < 32) acc += pk * w1[k * 32 + lane];
    }
    const float hmid = fmaxf(acc, 0.f);
    float acc2 = (lane < NCLS) ? b2[lane] : 0.f;
    #pragma unroll
    for (int k = 0; k < 32; k++) {
        const float hk = __shfl(hmid, k, 64);
        if (lane < NCLS) acc2 += hk * w2[k * NCLS + lane];
    }
    if (lane < NCLS) out[(size_t)g * NCLS + lane] = acc2;
}

// ===========================================================================
extern "C" void kernel_launch(void* const* d_in, const int* in_sizes, int n_in,
                              void* d_out, int out_size, void* d_ws, size_t ws_size,
                              hipStream_t stream) {
    const float* x     = (const float*)d_in[0];
    const int*   ei    = (const int*)d_in[1];
    const int*   batch = (const int*)d_in[2];
    const float* emb_w = (const float*)d_in[3];
    const float* emb_b = (const float*)d_in[4];
    const float* ibn_g = (const float*)d_in[5];
    const float* ibn_b = (const float*)d_in[6];
    const float* ibn_m = (const float*)d_in[7];
    const float* ibn_v = (const float*)d_in[8];
    const float* fc1_w = (const float*)d_in[9];
    const float* fc1_b = (const float*)d_in[10];
    const float* mbn_g = (const float*)d_in[11];
    const float* mbn_b = (const float*)d_in[12];
    const float* mbn_m = (const float*)d_in[13];
    const float* mbn_v = (const float*)d_in[14];
    const float* fc2_w = (const float*)d_in[15];
    const float* fc2_b = (const float*)d_in[16];
    const float* obn_g = (const float*)d_in[17];
    const float* obn_b = (const float*)d_in[18];
    const float* obn_m = (const float*)d_in[19];
    const float* obn_v = (const float*)d_in[20];
    const float* cls1w = (const float*)d_in[21];
    const float* cls1b = (const float*)d_in[22];
    const float* cls2w = (const float*)d_in[23];
    const float* cls2b = (const float*)d_in[24];

    float* h0     = (float*)d_ws;
    float* h1     = h0 + (size_t)N_NODES * HID;
    float* pooled = h1 + (size_t)N_NODES * HID;
    float* cnt    = pooled + NGRAPH * HID;
    int*   deg    = (int*)(cnt + NGRAPH);
    int*   offs   = deg + N_NODES;
    int*   bsum   = offs + (N_NODES + 1);
    int*   boff   = bsum + NBLK_SCAN;
    int*   csr    = boff + NBLK_SCAN;
    unsigned short* wpe = (unsigned short*)(csr + N_EDGES);   // 16384
    unsigned short* wpf = wpe + 16384;                        // 49152
    int*   goffs  = (int*)(wpf + 49152);                      // NGRAPH+1
    int*   gcnt   = goffs + (NGRAPH + 1);                     // NBKT
    // ebin (packed u32) reuses h0 space: CSR build completes before embed
    // writes h0. 128*12288*4 B = 6.3 MB << 51.2 MB.
    unsigned* ebin = (unsigned*)h0;

    const int* src = ei;
    const int* dst = ei + N_EDGES;

    // weight prep + graph offsets + gcnt zero (fused)
    setup_kernel<<<261, 256, 0, stream>>>(emb_w, wpe, fc1_w, fc2_w, wpf,
                                          batch, goffs, gcnt);

    // binned CSR build
    bin_kernel<<<NB_BIN, 256, 0, stream>>>(src, dst, gcnt, ebin);
    bindeg_kernel<<<NBKT, 512, 0, stream>>>(gcnt, ebin, deg);
    scan_sum_kernel<<<NBLK_SCAN, 256, 0, stream>>>(deg, bsum);
    scan_block_kernel<<<1, 256, 0, stream>>>(bsum, boff, offs);
    scan_scatter_kernel<<<NBLK_SCAN, 256, 0, stream>>>(deg, boff, offs);
    binscatter_kernel<<<NBKT, 512, 0, stream>>>(gcnt, ebin, offs, csr);

    // network
    const int gemm_blocks = N_NODES / TILE_N;   // 3125
    embed_kernel<<<gemm_blocks, 256, 0, stream>>>(x, wpe, emb_b,
                                                  ibn_g, ibn_b, ibn_m, ibn_v, h0);

    const float* hin = h0;
    float* hout = h1;
    for (int i = 0; i < 3; i++) {
        agg_mlp_kernel<<<gemm_blocks, 256, 0, stream>>>(
            hin, hout, offs, csr,
            wpf + (size_t)(i * 2 + 0) * 8192, wpf + (size_t)(i * 2 + 1) * 8192,
            fc1_b + i * HID, mbn_g + i * HID, mbn_b + i * HID, mbn_m + i * HID, mbn_v + i * HID,
            fc2_b + i * HID, obn_g + i * HID, obn_b + i * HID, obn_m + i * HID, obn_v + i * HID);
        const float* tmp = hin; hin = hout; hout = (float*)tmp;
    }

    // pool: one block per graph, no atomics
    pool_kernel<<<NGRAPH, 256, 0, stream>>>(h1, goffs, pooled, cnt);

    cls_kernel<<<NGRAPH, 64, 0, stream>>>(pooled, cnt, cls1w, cls1b, cls2w, cls2b,
                                          (float*)d_out);
}

// Round 7
// 465.701 us; speedup vs baseline: 1.0982x; 1.0655x over previous
//
#include <hip/hip_runtime.h>
#include <hip/hip_bf16.h>

#define N_NODES 200000
#define N_EDGES 1200000
#define IN_DIM  128
#define HID     64
#define NGRAPH  1024
#define NCLS    6
#define BN_EPS  1e-5f

#define TILE_N   64
#define ZS       68          // Ztmp row stride (floats); 272B = 17 banks shift, 2-way max
#define ECAP     1024

// ---- binned CSR build ----
#define NBKT   128           // dst-range buckets
#define BRANGE 1568          // nodes per bucket (128*1568 = 200704 >= N)
#define BCAP   12288         // per-bucket edge capacity (mean 9408, sigma ~97)
#define EPB    4096          // edges per bin_kernel block
#define NB_BIN ((N_EDGES + EPB - 1) / EPB)   // 293
// packed ebin entry: src (18b) | dstLocal (11b) << 18

// 16B-slot XOR swizzle for A-frag LDS
#define SWZ(s) ((s) ^ (((s) >> 4) & 3))

typedef short bf16x8 __attribute__((ext_vector_type(8)));
typedef float f32x4  __attribute__((ext_vector_type(4)));
#define MFMA16(a,b,c) __builtin_amdgcn_mfma_f32_16x16x32_bf16((a),(b),(c),0,0,0)

template<bool V> struct BoolC { static constexpr bool value = V; };

__device__ __forceinline__ unsigned short f2bf(float f) {
    union { __hip_bfloat16 h; unsigned short u; } v; v.h = __float2bfloat16(f); return v.u;
}
__device__ __forceinline__ float bfbits2f(unsigned short u) {
    union { unsigned int i; float f; } v; v.i = ((unsigned int)u) << 16; return v.f;
}
// f32x4 -> (hi bf16x4, lo bf16x4) packed as uint2 each
__device__ __forceinline__ void cvt4(const f32x4& x, uint2& hi, uint2& lo) {
    const unsigned short h0 = f2bf(x[0]), h1 = f2bf(x[1]), h2 = f2bf(x[2]), h3 = f2bf(x[3]);
    hi.x = (unsigned)h0 | ((unsigned)h1 << 16);
    hi.y = (unsigned)h2 | ((unsigned)h3 << 16);
    const unsigned short l0 = f2bf(x[0] - bfbits2f(h0)), l1 = f2bf(x[1] - bfbits2f(h1));
    const unsigned short l2 = f2bf(x[2] - bfbits2f(h2)), l3 = f2bf(x[3] - bfbits2f(h3));
    lo.x = (unsigned)l0 | ((unsigned)l1 << 16);
    lo.y = (unsigned)l2 | ((unsigned)l3 << 16);
}

// ===========================================================================
// Setup kernel: prep_emb (blocks 0..63) + prep_fc (64..255) + graph_offs /
// gcnt zero (256..260). Weight B-frag packing, bf16 hi/lo planes.
// ===========================================================================
__global__ __launch_bounds__(256) void setup_kernel(
    const float* __restrict__ emb_w, unsigned short* __restrict__ wpe,
    const float* __restrict__ fc1, const float* __restrict__ fc2,
    unsigned short* __restrict__ wpf,
    const int* __restrict__ batch, int* __restrict__ goffs,
    int* __restrict__ gcnt)
{
    const int b = blockIdx.x, t = threadIdx.x;
    if (b < 64) {
        const int idx = b * 256 + t;                     // [ct2][s2][p1][l6][j3]
        const int j = idx & 7, l = (idx >> 3) & 63;
        const int plane = (idx >> 9) & 1, s = (idx >> 10) & 3, ct = (idx >> 12) & 3;
        const int n = ct * 16 + (l & 15);
        const int k = s * 32 + (l >> 4) * 8 + j;
        const float f = emb_w[k * 64 + n];
        const unsigned short hb = f2bf(f);
        wpe[idx] = plane ? f2bf(f - bfbits2f(hb)) : hb;
    } else if (b < 256) {
        const int idx = (b - 64) * 256 + t;              // [layer][g][ct2][s1][p1][l6][j3]
        const int j = idx & 7, l = (idx >> 3) & 63;
        const int plane = (idx >> 9) & 1, s = (idx >> 10) & 1, ct = (idx >> 11) & 3;
        const int g = (idx >> 13) & 1, layer = idx >> 14;
        const int n = ct * 16 + (l & 15);
        const int k = s * 32 + (l >> 4) * 8 + j;
        const float* W = g ? fc2 : fc1;
        const float f = W[(layer * 64 + k) * 64 + n];
        const unsigned short hb = f2bf(f);
        wpf[idx] = plane ? f2bf(f - bfbits2f(hb)) : hb;
    } else {
        if (b == 256 && t < NBKT) gcnt[t] = 0;
        const int g = (b - 256) * 256 + t;
        if (g > NGRAPH) return;
        if (g == NGRAPH) { goffs[NGRAPH] = N_NODES; return; }
        int lo = 0, hi = N_NODES;
        while (lo < hi) {
            const int mid = (lo + hi) >> 1;
            if (batch[mid] < g) lo = mid + 1; else hi = mid;
        }
        goffs[g] = lo;
    }
}

// ===========================================================================
// Binned CSR build. Bulk streams NT (truly read/write-once); ebin packed 4 B.
// ===========================================================================
__global__ __launch_bounds__(256) void bin_kernel(
    const int* __restrict__ src, const int* __restrict__ dst,
    int* __restrict__ gcnt, unsigned* __restrict__ ebin)
{
    __shared__ int hist[NBKT];
    __shared__ int basis[NBKT];
    const int t = threadIdx.x;
    const int base = blockIdx.x * EPB;
    if (t < NBKT) hist[t] = 0;
    __syncthreads();
    int sv[16], dv[16];
    #pragma unroll
    for (int i = 0; i < 16; i++) {
        const int e = base + t + i * 256;
        if (e < N_EDGES) {
            sv[i] = __builtin_nontemporal_load(&src[e]);
            dv[i] = __builtin_nontemporal_load(&dst[e]);
            atomicAdd(&hist[dv[i] / BRANGE], 1);
        } else { sv[i] = -1; dv[i] = -1; }
    }
    __syncthreads();
    if (t < NBKT) { basis[t] = atomicAdd(&gcnt[t], hist[t]); hist[t] = 0; }
    __syncthreads();
    #pragma unroll
    for (int i = 0; i < 16; i++) {
        if (dv[i] >= 0) {
            const int bb = dv[i] / BRANGE;
            const int dl = dv[i] - bb * BRANGE;
            const int pos = basis[bb] + atomicAdd(&hist[bb], 1);
            __builtin_nontemporal_store(
                (unsigned)sv[i] | ((unsigned)dl << 18),
                &ebin[(size_t)bb * BCAP + pos]);
        }
    }
}

// ===========================================================================
// binoffs: per-bucket histogram + in-kernel 2-level prefix scan -> offs
// directly. Replaces bindeg + scan_sum + scan_block + scan_scatter.
// bucketBase computed redundantly per block from gcnt (128 ints, L2-hot).
// ===========================================================================
__global__ __launch_bounds__(512) void binoffs_kernel(
    const int* __restrict__ gcnt, const unsigned* __restrict__ ebin,
    int* __restrict__ offs)
{
    __shared__ int hist[BRANGE];
    __shared__ int bscan[NBKT];
    __shared__ int pscan[512];
    const int b = blockIdx.x, t = threadIdx.x;
    for (int i = t; i < BRANGE; i += 512) hist[i] = 0;
    if (t < NBKT) bscan[t] = gcnt[t];
    __syncthreads();
    const int cnt = gcnt[b];
    const unsigned* __restrict__ eb = ebin + (size_t)b * BCAP;
    for (int i = t; i < cnt; i += 512) {
        const unsigned e = __builtin_nontemporal_load(&eb[i]);
        atomicAdd(&hist[e >> 18], 1);
    }
    __syncthreads();
    // inclusive scan over the 128 bucket counts (Hillis-Steele)
    for (int off = 1; off < NBKT; off <<= 1) {
        const int u = (t >= off && t < NBKT) ? bscan[t - off] : 0;
        __syncthreads();
        if (t < NBKT) bscan[t] += u;
        __syncthreads();
    }
    const int bucketBase = (b == 0) ? 0 : bscan[b - 1];
    // per-thread chunk of 4 nodes, then 512-wide scan
    const int i0 = t * 4;
    const int h0v = (i0 + 0 < BRANGE) ? hist[i0 + 0] : 0;
    const int h1v = (i0 + 1 < BRANGE) ? hist[i0 + 1] : 0;
    const int h2v = (i0 + 2 < BRANGE) ? hist[i0 + 2] : 0;
    const int h3v = (i0 + 3 < BRANGE) ? hist[i0 + 3] : 0;
    const int ts = h0v + h1v + h2v + h3v;
    pscan[t] = ts;
    __syncthreads();
    for (int off = 1; off < 512; off <<= 1) {
        const int u = (t >= off) ? pscan[t - off] : 0;
        __syncthreads();
        pscan[t] += u;
        __syncthreads();
    }
    const int excl = pscan[t] - ts + bucketBase;
    const int r0 = b * BRANGE;
    if (i0 + 0 < BRANGE && r0 + i0 + 0 < N_NODES) offs[r0 + i0 + 0] = excl;
    if (i0 + 1 < BRANGE && r0 + i0 + 1 < N_NODES) offs[r0 + i0 + 1] = excl + h0v;
    if (i0 + 2 < BRANGE && r0 + i0 + 2 < N_NODES) offs[r0 + i0 + 2] = excl + h0v + h1v;
    if (i0 + 3 < BRANGE && r0 + i0 + 3 < N_NODES) offs[r0 + i0 + 3] = excl + h0v + h1v + h2v;
    if (b == NBKT - 1 && t == 0) offs[N_NODES] = N_EDGES;
}

// binscatter: one block owns one bucket's contiguous csr region; cursors in LDS.
__global__ __launch_bounds__(512) void binscatter_kernel(
    const int* __restrict__ gcnt, const unsigned* __restrict__ ebin,
    const int* __restrict__ offs, int* __restrict__ csr_src)
{
    __shared__ int cur[BRANGE];
    const int b = blockIdx.x, t = threadIdx.x;
    const int r0 = b * BRANGE;
    const int lim = (r0 + BRANGE <= N_NODES) ? BRANGE : (N_NODES - r0);
    for (int i = t; i < lim; i += 512) cur[i] = offs[r0 + i];
    __syncthreads();
    const int cnt = gcnt[b];
    const unsigned* __restrict__ eb = ebin + (size_t)b * BCAP;
    for (int i = t; i < cnt; i += 512) {
        const unsigned e = __builtin_nontemporal_load(&eb[i]);
        const int pos = atomicAdd(&cur[e >> 18], 1);
        csr_src[pos] = (int)(e & 0x3FFFFu);
    }
}

// ===========================================================================
// Embed: h0 = relu(bn(x @ W + b)) via split-bf16 MFMA.
// x NT-read (true stream); h0 store NORMAL (layer-1 gather prefill).
// ===========================================================================
__global__ __launch_bounds__(256) void embed_kernel(
    const float* __restrict__ x, const unsigned short* __restrict__ wpe,
    const float* __restrict__ bias,
    const float* __restrict__ bn_g, const float* __restrict__ bn_b,
    const float* __restrict__ bn_m, const float* __restrict__ bn_v,
    float* __restrict__ h)
{
    __shared__ __align__(16) float Ush[8192];                  // 32 KB union
    __shared__ float BNs[128];
    short* Abuf = (short*)Ush;
    float* Ztmp = Ush;
    const int t = threadIdx.x, lane = t & 63, w = t >> 6;
    const int base = blockIdx.x * TILE_N;

    if (t < 64) {
        const float s = bn_g[t] * rsqrtf(bn_v[t] + BN_EPS);
        BNs[t] = s;
        BNs[64 + t] = bias[t] * s + bn_b[t] - bn_m[t] * s;
    }
    // stage + hi/lo convert x tile into A-frag order (swizzled slots)
    #pragma unroll
    for (int i = 0; i < 8; i++) {
        const int idx = t + i * 256;                 // 0..2047
        const int n = idx >> 5, k4 = idx & 31;
        const f32x4 v = __builtin_nontemporal_load(
            (const f32x4*)(x + (size_t)(base + n) * IN_DIM + k4 * 4));
        uint2 hi, lo; cvt4(v, hi, lo);
        const int s = k4 >> 3, lc = (n & 15) + 16 * ((k4 >> 1) & 3);
        const int half = k4 & 1, wm = n >> 4;
        const int sl0 = ((wm * 4 + s) * 2 + 0) * 64 + lc;
        const int sl1 = ((wm * 4 + s) * 2 + 1) * 64 + lc;
        *(uint2*)&Abuf[SWZ(sl0) * 8 + half * 4] = hi;
        *(uint2*)&Abuf[SWZ(sl1) * 8 + half * 4] = lo;
    }
    __syncthreads();

    const bf16x8* A = (const bf16x8*)Abuf;
    const bf16x8* B = (const bf16x8*)wpe;
    bf16x8 ah[4], al[4];
    #pragma unroll
    for (int s = 0; s < 4; s++) {
        ah[s] = A[SWZ(((w * 4 + s) * 2 + 0) * 64 + lane)];
        al[s] = A[SWZ(((w * 4 + s) * 2 + 1) * 64 + lane)];
    }
    __syncthreads();    // all frag reads done; Ztmp may overwrite Abuf
    const int q = lane >> 4, c = lane & 15;
    #pragma unroll
    for (int ct = 0; ct < 4; ct++) {
        f32x4 acc = {0.f, 0.f, 0.f, 0.f};
        #pragma unroll
        for (int s = 0; s < 4; s++) {
            const bf16x8 bh = B[(ct << 9) + (s << 7) + lane];
            const bf16x8 bl = B[(ct << 9) + (s << 7) + 64 + lane];
            acc = MFMA16(ah[s], bh, acc);
            acc = MFMA16(ah[s], bl, acc);
            acc = MFMA16(al[s], bh, acc);
        }
        const int n = ct * 16 + c;
        const float sc = BNs[n], sh = BNs[64 + n];
        #pragma unroll
        for (int r = 0; r < 4; r++)
            Ztmp[(w * 16 + q * 4 + r) * ZS + n] = fmaxf(acc[r] * sc + sh, 0.f);
    }
    __syncthreads();
    #pragma unroll
    for (int i = 0; i < 4; i++) {
        const int idx = t + i * 256, n = idx >> 4, k4 = idx & 15;
        *(f32x4*)(h + (size_t)(base + n) * HID + k4 * 4) =
            *(const f32x4*)(&Ztmp[n * ZS + k4 * 4]);
    }
}

// ===========================================================================
// Fused GIN layer. h accesses CACHED (h rows carry gather reuse). allLds
// branch removes the per-edge predicated csr[] load. 6 blocks/CU (7 thrashed
// L2: r6 FETCH+6MB, WRITE+12MB). POOL=true (last layer): pool directly from
// Ztmp into pooled[] via atomics, skip the 51MB hout store + pool_kernel.
// ===========================================================================
template<bool POOL>
__global__ __launch_bounds__(256, 6) void agg_mlp_kernel(
    const float* __restrict__ hin, float* __restrict__ hout,
    const int* __restrict__ offs, const int* __restrict__ csr,
    const int* __restrict__ batch, float* __restrict__ pooled,
    const unsigned short* __restrict__ wp1, const unsigned short* __restrict__ wp2,
    const float* __restrict__ b1, const float* __restrict__ g1,
    const float* __restrict__ bb1, const float* __restrict__ m1, const float* __restrict__ v1,
    const float* __restrict__ b2, const float* __restrict__ g2,
    const float* __restrict__ bb2, const float* __restrict__ m2, const float* __restrict__ v2)
{
    __shared__ __align__(16) float Ush[TILE_N * ZS];           // 17408 B union
    __shared__ int   OF[TILE_N + 1];
    __shared__ int   EIDX[ECAP];                               // 4 KB
    __shared__ float BNs[256];
    __shared__ int   GID[TILE_N];
    short* Abuf = (short*)Ush;
    float* Ztmp = Ush;
    const int t = threadIdx.x, lane = t & 63, w = t >> 6;
    const int sub = lane >> 4, cq = lane & 15;
    const int base = blockIdx.x * TILE_N;

    if (t < 64) {
        const float sa = g1[t] * rsqrtf(v1[t] + BN_EPS);
        BNs[t] = sa; BNs[64 + t] = b1[t] * sa + bb1[t] - m1[t] * sa;
        const float sb = g2[t] * rsqrtf(v2[t] + BN_EPS);
        BNs[128 + t] = sb; BNs[192 + t] = b2[t] * sb + bb2[t] - m2[t] * sb;
        if (POOL) GID[t] = batch[base + t];
    }
    if (t <= TILE_N) OF[t] = offs[base + t];
    const int segStart = offs[base];
    const int segEnd   = offs[base + TILE_N];
    for (int i = t; i < segEnd - segStart; i += 256)
        if (i < ECAP) EIDX[i] = csr[segStart + i];
    __syncthreads();

    // gather -> A-frag hi/lo writes (swizzled slots)
    // two chains (A,B) advance together: 8 independent loads per wait
    const float* __restrict__ hc = hin + cq * 4;
    const bool allLds = (segEnd - segStart) <= ECAP;   // true for ~all tiles

    auto gather_pass = [&](auto ldsTag) {
        constexpr bool LDSONLY = decltype(ldsTag)::value;
        #pragma unroll
        for (int pp = 0; pp < 2; pp++) {
            const int mlA = (pp * 2 + 0) * 4 + sub;
            const int mlB = (pp * 2 + 1) * 4 + sub;
            const int nlA = w * 16 + mlA, nlB = w * 16 + mlB;
            int eA = OF[nlA]; const int eA1 = OF[nlA + 1];
            int eB = OF[nlB]; const int eB1 = OF[nlB + 1];
            // clamp targets stay inside [segStart, segEnd): deg-0-safe
            const int eAm = (eA1 - 1 > segStart) ? eA1 - 1 : segStart;
            const int eBm = (eB1 - 1 > segStart) ? eB1 - 1 : segStart;
            f32x4 accA = *(const f32x4*)(hin + (size_t)(base + nlA) * HID + cq * 4);
            f32x4 accB = *(const f32x4*)(hin + (size_t)(base + nlB) * HID + cq * 4);
            while (eA < eA1 || eB < eB1) {
                int ia[4], ib[4];
                #pragma unroll
                for (int k = 0; k < 4; k++) {
                    const int ea = (eA + k < eAm) ? eA + k : eAm;
                    const int eb = (eB + k < eBm) ? eB + k : eBm;
                    const int la = ea - segStart, lb = eb - segStart;
                    if (LDSONLY) {
                        ia[k] = EIDX[la];
                        ib[k] = EIDX[lb];
                    } else {
                        ia[k] = (la < ECAP) ? EIDX[la] : csr[ea];
                        ib[k] = (lb < ECAP) ? EIDX[lb] : csr[eb];
                    }
                }
                f32x4 va[4], vb[4];
                #pragma unroll
                for (int k = 0; k < 4; k++) {
                    va[k] = *(const f32x4*)(hc + (size_t)ia[k] * HID);
                    vb[k] = *(const f32x4*)(hc + (size_t)ib[k] * HID);
                }
                #pragma unroll
                for (int k = 0; k < 4; k++) {
                    const float ma = (eA + k < eA1) ? 1.f : 0.f;
                    const float mb = (eB + k < eB1) ? 1.f : 0.f;
                    accA += va[k] * ma;
                    accB += vb[k] * mb;
                }
                eA += 4; eB += 4;
            }
            {
                uint2 hi, lo; cvt4(accA, hi, lo);
                const int s = cq >> 3, lc = mlA + 16 * ((cq >> 1) & 3), half = cq & 1;
                const int sl0 = ((w * 2 + s) * 2 + 0) * 64 + lc;
                const int sl1 = ((w * 2 + s) * 2 + 1) * 64 + lc;
                *(uint2*)&Abuf[SWZ(sl0) * 8 + half * 4] = hi;
                *(uint2*)&Abuf[SWZ(sl1) * 8 + half * 4] = lo;
            }
            {
                uint2 hi, lo; cvt4(accB, hi, lo);
                const int s = cq >> 3, lc = mlB + 16 * ((cq >> 1) & 3), half = cq & 1;
                const int sl0 = ((w * 2 + s) * 2 + 0) * 64 + lc;
                const int sl1 = ((w * 2 + s) * 2 + 1) * 64 + lc;
                *(uint2*)&Abuf[SWZ(sl0) * 8 + half * 4] = hi;
                *(uint2*)&Abuf[SWZ(sl1) * 8 + half * 4] = lo;
            }
        }
    };
    if (allLds) gather_pass(BoolC<true>{});
    else        gather_pass(BoolC<false>{});
    __syncthreads();

    const bf16x8* A = (const bf16x8*)Abuf;
    const int q = lane >> 4, c = lane & 15;

    // GEMM1
    {
        const bf16x8 a0h = A[SWZ(((w * 2 + 0) * 2 + 0) * 64 + lane)];
        const bf16x8 a0l = A[SWZ(((w * 2 + 0) * 2 + 1) * 64 + lane)];
        const bf16x8 a1h = A[SWZ(((w * 2 + 1) * 2 + 0) * 64 + lane)];
        const bf16x8 a1l = A[SWZ(((w * 2 + 1) * 2 + 1) * 64 + lane)];
        __syncthreads();    // frag reads done; Ztmp writes may alias Abuf
        const bf16x8* B = (const bf16x8*)wp1;
        #pragma unroll
        for (int ct = 0; ct < 4; ct++) {
            const bf16x8 b0h = B[(ct << 8) + lane];
            const bf16x8 b0l = B[(ct << 8) + 64 + lane];
            const bf16x8 b1h_ = B[(ct << 8) + 128 + lane];
            const bf16x8 b1l_ = B[(ct << 8) + 192 + lane];
            f32x4 acc = {0.f, 0.f, 0.f, 0.f};
            acc = MFMA16(a0h, b0h, acc);
            acc = MFMA16(a0h, b0l, acc);
            acc = MFMA16(a0l, b0h, acc);
            acc = MFMA16(a1h, b1h_, acc);
            acc = MFMA16(a1h, b1l_, acc);
            acc = MFMA16(a1l, b1h_, acc);
            const int n = ct * 16 + c;
            const float sc = BNs[n], sh = BNs[64 + n];
            #pragma unroll
            for (int r = 0; r < 4; r++)
                Ztmp[(w * 16 + q * 4 + r) * ZS + n] = fmaxf(acc[r] * sc + sh, 0.f);
        }
    }
    __syncthreads();    // Ztmp complete

    // re-split t1 into A-frags (register-staged: read all, barrier, write)
    {
        const int m = t >> 2;
        f32x4 vv[4];
        #pragma unroll
        for (int d = 0; d < 4; d++) {
            const int k4 = (t & 3) * 4 + d;
            vv[d] = *(const f32x4*)(&Ztmp[m * ZS + k4 * 4]);
        }
        __syncthreads();    // Ztmp reads done; A-frag writes may alias
        #pragma unroll
        for (int d = 0; d < 4; d++) {
            const int k4 = (t & 3) * 4 + d;
            uint2 hi, lo; cvt4(vv[d], hi, lo);
            const int s = k4 >> 3, lc = (m & 15) + 16 * ((k4 >> 1) & 3);
            const int half = k4 & 1, wm = m >> 4;
            const int sl0 = ((wm * 2 + s) * 2 + 0) * 64 + lc;
            const int sl1 = ((wm * 2 + s) * 2 + 1) * 64 + lc;
            *(uint2*)&Abuf[SWZ(sl0) * 8 + half * 4] = hi;
            *(uint2*)&Abuf[SWZ(sl1) * 8 + half * 4] = lo;
        }
    }
    __syncthreads();

    // GEMM2
    {
        const bf16x8 a0h = A[SWZ(((w * 2 + 0) * 2 + 0) * 64 + lane)];
        const bf16x8 a0l = A[SWZ(((w * 2 + 0) * 2 + 1) * 64 + lane)];
        const bf16x8 a1h = A[SWZ(((w * 2 + 1) * 2 + 0) * 64 + lane)];
        const bf16x8 a1l = A[SWZ(((w * 2 + 1) * 2 + 1) * 64 + lane)];
        __syncthreads();    // frag reads done; Ztmp writes may alias Abuf
        const bf16x8* B = (const bf16x8*)wp2;
        #pragma unroll
        for (int ct = 0; ct < 4; ct++) {
            const bf16x8 b0h = B[(ct << 8) + lane];
            const bf16x8 b0l = B[(ct << 8) + 64 + lane];
            const bf16x8 b1h_ = B[(ct << 8) + 128 + lane];
            const bf16x8 b1l_ = B[(ct << 8) + 192 + lane];
            f32x4 acc = {0.f, 0.f, 0.f, 0.f};
            acc = MFMA16(a0h, b0h, acc);
            acc = MFMA16(a0h, b0l, acc);
            acc = MFMA16(a0l, b0h, acc);
            acc = MFMA16(a1h, b1h_, acc);
            acc = MFMA16(a1h, b1l_, acc);
            acc = MFMA16(a1l, b1h_, acc);
            const int n = ct * 16 + c;
            const float sc = BNs[128 + n], sh = BNs[192 + n];
            #pragma unroll
            for (int r = 0; r < 4; r++)
                Ztmp[(w * 16 + q * 4 + r) * ZS + n] = fmaxf(acc[r] * sc + sh, 0.f);
        }
    }
    __syncthreads();

    if (POOL) {
        // pool directly from Ztmp: thread (c = t&63, rg = t>>6) run-sums its
        // 16 rows' column c grouped by graph id -> <=3 atomics per thread
        // into the L2-resident pooled[1024][64].
        const int cc = t & 63, rg = t >> 6;
        float run = 0.f;
        int cur = GID[rg * 16];
        #pragma unroll
        for (int r = 0; r < 16; r++) {
            const int row = rg * 16 + r;
            const int g = GID[row];
            if (g != cur) {
                atomicAdd(&pooled[(size_t)cur * HID + cc], run);
                run = 0.f; cur = g;
            }
            run += Ztmp[row * ZS + cc];
        }
        atomicAdd(&pooled[(size_t)cur * HID + cc], run);
    } else {
        #pragma unroll
        for (int i = 0; i < 4; i++) {
            const int idx = t + i * 256, n = idx >> 4, k4 = idx & 15;
            *(f32x4*)(hout + (size_t)(base + n) * HID + k4 * 4) =
                *(const f32x4*)(&Ztmp[n * ZS + k4 * 4]);
        }
    }
}

// ===========================================================================
// Classifier: cnt derived from goffs (pool_kernel removed).
// ===========================================================================
__global__ __launch_bounds__(64) void cls_kernel(
    const float* __restrict__ pooled, const int* __restrict__ goffs,
    const float* __restrict__ w1, const float* __restrict__ b1,
    const float* __restrict__ w2, const float* __restrict__ b2,
    float* __restrict__ out)
{
    const int g = blockIdx.x;
    const int lane = threadIdx.x;
    const float c = (float)(goffs[g + 1] - goffs[g]);
    const float p = pooled[(size_t)g * HID + lane] / fmaxf(c, 1.f);
    float acc = (lane < 32) ? b1[lane] : 0.f;
    #pragma unroll
    for (int k = 0; k < 64; k++) {
        const float pk = __shfl(p, k, 64);
        if (lane < 32) acc += pk * w1[k * 32 + lane];
    }
    const float hmid = fmaxf(acc, 0.f);
    float acc2 = (lane < NCLS) ? b2[lane] : 0.f;
    #pragma unroll
    for (int k = 0; k < 32; k++) {
        const float hk = __shfl(hmid, k, 64);
        if (lane < NCLS) acc2 += hk * w2[k * NCLS + lane];
    }
    if (lane < NCLS) out[(size_t)g * NCLS + lane] = acc2;
}

// ===========================================================================
extern "C" void kernel_launch(void* const* d_in, const int* in_sizes, int n_in,
                              void* d_out, int out_size, void* d_ws, size_t ws_size,
                              hipStream_t stream) {
    const float* x     = (const float*)d_in[0];
    const int*   ei    = (const int*)d_in[1];
    const int*   batch = (const int*)d_in[2];
    const float* emb_w = (const float*)d_in[3];
    const float* emb_b = (const float*)d_in[4];
    const float* ibn_g = (const float*)d_in[5];
    const float* ibn_b = (const float*)d_in[6];
    const float* ibn_m = (const float*)d_in[7];
    const float* ibn_v = (const float*)d_in[8];
    const float* fc1_w = (const float*)d_in[9];
    const float* fc1_b = (const float*)d_in[10];
    const float* mbn_g = (const float*)d_in[11];
    const float* mbn_b = (const float*)d_in[12];
    const float* mbn_m = (const float*)d_in[13];
    const float* mbn_v = (const float*)d_in[14];
    const float* fc2_w = (const float*)d_in[15];
    const float* fc2_b = (const float*)d_in[16];
    const float* obn_g = (const float*)d_in[17];
    const float* obn_b = (const float*)d_in[18];
    const float* obn_m = (const float*)d_in[19];
    const float* obn_v = (const float*)d_in[20];
    const float* cls1w = (const float*)d_in[21];
    const float* cls1b = (const float*)d_in[22];
    const float* cls2w = (const float*)d_in[23];
    const float* cls2b = (const float*)d_in[24];

    float* h0     = (float*)d_ws;
    float* h1     = h0 + (size_t)N_NODES * HID;
    float* pooled = h1 + (size_t)N_NODES * HID;
    float* cnt    = pooled + NGRAPH * HID;            // unused (kept for layout)
    int*   deg    = (int*)(cnt + NGRAPH);             // unused (kept for layout)
    int*   offs   = deg + N_NODES;
    int*   bsum   = offs + (N_NODES + 1);             // unused
    int*   boff   = bsum + 256;                       // unused
    int*   csr    = boff + 256;
    unsigned short* wpe = (unsigned short*)(csr + N_EDGES);   // 16384
    unsigned short* wpf = wpe + 16384;                        // 49152
    int*   goffs  = (int*)(wpf + 49152);                      // NGRAPH+1
    int*   gcnt   = goffs + (NGRAPH + 1);                     // NBKT
    // ebin (packed u32) reuses h0 space: CSR build completes before embed
    // writes h0. 128*12288*4 B = 6.3 MB << 51.2 MB.
    unsigned* ebin = (unsigned*)h0;

    const int* src = ei;
    const int* dst = ei + N_EDGES;

    // weight prep + graph offsets + gcnt zero (fused); pooled zeroed for the
    // fused-pool atomics in the last GIN layer.
    setup_kernel<<<261, 256, 0, stream>>>(emb_w, wpe, fc1_w, fc2_w, wpf,
                                          batch, goffs, gcnt);
    hipMemsetAsync(pooled, 0, (size_t)NGRAPH * HID * sizeof(float), stream);

    // binned CSR build (offs computed in-kernel; scans removed)
    bin_kernel<<<NB_BIN, 256, 0, stream>>>(src, dst, gcnt, ebin);
    binoffs_kernel<<<NBKT, 512, 0, stream>>>(gcnt, ebin, offs);
    binscatter_kernel<<<NBKT, 512, 0, stream>>>(gcnt, ebin, offs, csr);

    // network
    const int gemm_blocks = N_NODES / TILE_N;   // 3125
    embed_kernel<<<gemm_blocks, 256, 0, stream>>>(x, wpe, emb_b,
                                                  ibn_g, ibn_b, ibn_m, ibn_v, h0);

    const float* hin = h0;
    float* hout = h1;
    for (int i = 0; i < 3; i++) {
        if (i < 2)
            agg_mlp_kernel<false><<<gemm_blocks, 256, 0, stream>>>(
                hin, hout, offs, csr, batch, pooled,
                wpf + (size_t)(i * 2 + 0) * 8192, wpf + (size_t)(i * 2 + 1) * 8192,
                fc1_b + i * HID, mbn_g + i * HID, mbn_b + i * HID, mbn_m + i * HID, mbn_v + i * HID,
                fc2_b + i * HID, obn_g + i * HID, obn_b + i * HID, obn_m + i * HID, obn_v + i * HID);
        else
            agg_mlp_kernel<true><<<gemm_blocks, 256, 0, stream>>>(
                hin, hout, offs, csr, batch, pooled,
                wpf + (size_t)(i * 2 + 0) * 8192, wpf + (size_t)(i * 2 + 1) * 8192,
                fc1_b + i * HID, mbn_g + i * HID, mbn_b + i * HID, mbn_m + i * HID, mbn_v + i * HID,
                fc2_b + i * HID, obn_g + i * HID, obn_b + i * HID, obn_m + i * HID, obn_v + i * HID);
        const float* tmp = hin; hin = hout; hout = (float*)tmp;
    }

    cls_kernel<<<NGRAPH, 64, 0, stream>>>(pooled, goffs, cls1w, cls1b, cls2w, cls2b,
                                          (float*)d_out);
}

// Round 8
// 463.558 us; speedup vs baseline: 1.1032x; 1.0046x over previous
//
#include <hip/hip_runtime.h>
#include <hip/hip_bf16.h>

#define N_NODES 200000
#define N_EDGES 1200000
#define IN_DIM  128
#define HID     64
#define NGRAPH  1024
#define NCLS    6
#define BN_EPS  1e-5f

#define TILE_N   64
#define ZS       68          // Ztmp row stride (floats); 272B = 17 banks shift, 2-way max
#define ECAP     1024

// ---- binned CSR build ----
#define NBKT   128           // dst-range buckets
#define BRANGE 1568          // nodes per bucket (128*1568 = 200704 >= N)
#define BCAP   12288         // per-bucket edge capacity (mean 9408, sigma ~97)
#define EPB    4096          // edges per bin block
#define NB_BIN ((N_EDGES + EPB - 1) / EPB)   // 293
// packed ebin entry: src (18b) | dstLocal (11b) << 18

// 16B-slot XOR swizzle for A-frag LDS
#define SWZ(s) ((s) ^ (((s) >> 4) & 3))

typedef short bf16x8 __attribute__((ext_vector_type(8)));
typedef float f32x4  __attribute__((ext_vector_type(4)));
#define MFMA16(a,b,c) __builtin_amdgcn_mfma_f32_16x16x32_bf16((a),(b),(c),0,0,0)

template<bool V> struct BoolC { static constexpr bool value = V; };

__device__ __forceinline__ unsigned short f2bf(float f) {
    union { __hip_bfloat16 h; unsigned short u; } v; v.h = __float2bfloat16(f); return v.u;
}
__device__ __forceinline__ float bfbits2f(unsigned short u) {
    union { unsigned int i; float f; } v; v.i = ((unsigned int)u) << 16; return v.f;
}
// f32x4 -> (hi bf16x4, lo bf16x4) packed as uint2 each
__device__ __forceinline__ void cvt4(const f32x4& x, uint2& hi, uint2& lo) {
    const unsigned short h0 = f2bf(x[0]), h1 = f2bf(x[1]), h2 = f2bf(x[2]), h3 = f2bf(x[3]);
    hi.x = (unsigned)h0 | ((unsigned)h1 << 16);
    hi.y = (unsigned)h2 | ((unsigned)h3 << 16);
    const unsigned short l0 = f2bf(x[0] - bfbits2f(h0)), l1 = f2bf(x[1] - bfbits2f(h1));
    const unsigned short l2 = f2bf(x[2] - bfbits2f(h2)), l3 = f2bf(x[3] - bfbits2f(h3));
    lo.x = (unsigned)l0 | ((unsigned)l1 << 16);
    lo.y = (unsigned)l2 | ((unsigned)l3 << 16);
}

// ===========================================================================
// Setup kernel: prep_emb (blocks 0..63) + prep_fc (64..255) + graph_offs /
// gcnt zero (256..260) + pooled zero (261..324).
// ===========================================================================
__global__ __launch_bounds__(256) void setup_kernel(
    const float* __restrict__ emb_w, unsigned short* __restrict__ wpe,
    const float* __restrict__ fc1, const float* __restrict__ fc2,
    unsigned short* __restrict__ wpf,
    const int* __restrict__ batch, int* __restrict__ goffs,
    int* __restrict__ gcnt, float* __restrict__ pooled)
{
    const int b = blockIdx.x, t = threadIdx.x;
    if (b < 64) {
        const int idx = b * 256 + t;                     // [ct2][s2][p1][l6][j3]
        const int j = idx & 7, l = (idx >> 3) & 63;
        const int plane = (idx >> 9) & 1, s = (idx >> 10) & 3, ct = (idx >> 12) & 3;
        const int n = ct * 16 + (l & 15);
        const int k = s * 32 + (l >> 4) * 8 + j;
        const float f = emb_w[k * 64 + n];
        const unsigned short hb = f2bf(f);
        wpe[idx] = plane ? f2bf(f - bfbits2f(hb)) : hb;
    } else if (b < 256) {
        const int idx = (b - 64) * 256 + t;              // [layer][g][ct2][s1][p1][l6][j3]
        const int j = idx & 7, l = (idx >> 3) & 63;
        const int plane = (idx >> 9) & 1, s = (idx >> 10) & 1, ct = (idx >> 11) & 3;
        const int g = (idx >> 13) & 1, layer = idx >> 14;
        const int n = ct * 16 + (l & 15);
        const int k = s * 32 + (l >> 4) * 8 + j;
        const float* W = g ? fc2 : fc1;
        const float f = W[(layer * 64 + k) * 64 + n];
        const unsigned short hb = f2bf(f);
        wpf[idx] = plane ? f2bf(f - bfbits2f(hb)) : hb;
    } else if (b < 261) {
        if (b == 256 && t < NBKT) gcnt[t] = 0;
        const int g = (b - 256) * 256 + t;
        if (g > NGRAPH) return;
        if (g == NGRAPH) { goffs[NGRAPH] = N_NODES; return; }
        int lo = 0, hi = N_NODES;
        while (lo < hi) {
            const int mid = (lo + hi) >> 1;
            if (batch[mid] < g) lo = mid + 1; else hi = mid;
        }
        goffs[g] = lo;
    } else {
        const int idx = (b - 261) * 256 + t;             // 16384 float4s
        const f32x4 z = {0.f, 0.f, 0.f, 0.f};
        *(f32x4*)(pooled + (size_t)idx * 4) = z;
    }
}

// ===========================================================================
// Fused CSR-bin + embed. Blocks [0,NB_BIN): edge binning (293 blocks, hides
// under embed's 3125). Blocks [NB_BIN,..): embed tiles. Independent work —
// only agg layer 1 needs both. ebin aliases h1 (first written by agg1).
// ===========================================================================
__global__ __launch_bounds__(256) void csr_embed_kernel(
    const int* __restrict__ src, const int* __restrict__ dst,
    int* __restrict__ gcnt, unsigned* __restrict__ ebin,
    const float* __restrict__ x, const unsigned short* __restrict__ wpe,
    const float* __restrict__ bias,
    const float* __restrict__ bn_g, const float* __restrict__ bn_b,
    const float* __restrict__ bn_m, const float* __restrict__ bn_v,
    float* __restrict__ h)
{
    __shared__ __align__(16) float Ush[8192];                  // 32 KB union
    __shared__ float BNs[128];
    const int t = threadIdx.x;

    if (blockIdx.x < NB_BIN) {
        // ---- bin path (hist/basis carved from Ush) ----
        int* hist  = (int*)Ush;
        int* basis = hist + NBKT;
        const int base = blockIdx.x * EPB;
        if (t < NBKT) hist[t] = 0;
        __syncthreads();
        int sv[16], dv[16];
        #pragma unroll
        for (int i = 0; i < 16; i++) {
            const int e = base + t + i * 256;
            if (e < N_EDGES) {
                sv[i] = __builtin_nontemporal_load(&src[e]);
                dv[i] = __builtin_nontemporal_load(&dst[e]);
                atomicAdd(&hist[dv[i] / BRANGE], 1);
            } else { sv[i] = -1; dv[i] = -1; }
        }
        __syncthreads();
        if (t < NBKT) { basis[t] = atomicAdd(&gcnt[t], hist[t]); hist[t] = 0; }
        __syncthreads();
        #pragma unroll
        for (int i = 0; i < 16; i++) {
            if (dv[i] >= 0) {
                const int bb = dv[i] / BRANGE;
                const int dl = dv[i] - bb * BRANGE;
                const int pos = basis[bb] + atomicAdd(&hist[bb], 1);
                __builtin_nontemporal_store(
                    (unsigned)sv[i] | ((unsigned)dl << 18),
                    &ebin[(size_t)bb * BCAP + pos]);
            }
        }
        return;
    }

    // ---- embed path ----
    short* Abuf = (short*)Ush;
    float* Ztmp = Ush;
    const int lane = t & 63, w = t >> 6;
    const int base = (blockIdx.x - NB_BIN) * TILE_N;

    if (t < 64) {
        const float s = bn_g[t] * rsqrtf(bn_v[t] + BN_EPS);
        BNs[t] = s;
        BNs[64 + t] = bias[t] * s + bn_b[t] - bn_m[t] * s;
    }
    // stage + hi/lo convert x tile into A-frag order (swizzled slots)
    #pragma unroll
    for (int i = 0; i < 8; i++) {
        const int idx = t + i * 256;                 // 0..2047
        const int n = idx >> 5, k4 = idx & 31;
        const f32x4 v = __builtin_nontemporal_load(
            (const f32x4*)(x + (size_t)(base + n) * IN_DIM + k4 * 4));
        uint2 hi, lo; cvt4(v, hi, lo);
        const int s = k4 >> 3, lc = (n & 15) + 16 * ((k4 >> 1) & 3);
        const int half = k4 & 1, wm = n >> 4;
        const int sl0 = ((wm * 4 + s) * 2 + 0) * 64 + lc;
        const int sl1 = ((wm * 4 + s) * 2 + 1) * 64 + lc;
        *(uint2*)&Abuf[SWZ(sl0) * 8 + half * 4] = hi;
        *(uint2*)&Abuf[SWZ(sl1) * 8 + half * 4] = lo;
    }
    __syncthreads();

    const bf16x8* A = (const bf16x8*)Abuf;
    const bf16x8* B = (const bf16x8*)wpe;
    bf16x8 ah[4], al[4];
    #pragma unroll
    for (int s = 0; s < 4; s++) {
        ah[s] = A[SWZ(((w * 4 + s) * 2 + 0) * 64 + lane)];
        al[s] = A[SWZ(((w * 4 + s) * 2 + 1) * 64 + lane)];
    }
    __syncthreads();    // all frag reads done; Ztmp may overwrite Abuf
    const int q = lane >> 4, c = lane & 15;
    #pragma unroll
    for (int ct = 0; ct < 4; ct++) {
        f32x4 acc = {0.f, 0.f, 0.f, 0.f};
        #pragma unroll
        for (int s = 0; s < 4; s++) {
            const bf16x8 bh = B[(ct << 9) + (s << 7) + lane];
            const bf16x8 bl = B[(ct << 9) + (s << 7) + 64 + lane];
            acc = MFMA16(ah[s], bh, acc);
            acc = MFMA16(ah[s], bl, acc);
            acc = MFMA16(al[s], bh, acc);
        }
        const int n = ct * 16 + c;
        const float sc = BNs[n], sh = BNs[64 + n];
        #pragma unroll
        for (int r = 0; r < 4; r++)
            Ztmp[(w * 16 + q * 4 + r) * ZS + n] = fmaxf(acc[r] * sc + sh, 0.f);
    }
    __syncthreads();
    #pragma unroll
    for (int i = 0; i < 4; i++) {
        const int idx = t + i * 256, n = idx >> 4, k4 = idx & 15;
        *(f32x4*)(h + (size_t)(base + n) * HID + k4 * 4) =
            *(const f32x4*)(&Ztmp[n * ZS + k4 * 4]);
    }
}

// ===========================================================================
// Fused offs+scatter: one block per bucket. Stage packed edges in LDS (one
// ebin read instead of two), histogram, 2-level scan -> offs, rewrite hist
// as absolute cursors, scatter to csr straight from LDS.
// ===========================================================================
__global__ __launch_bounds__(512) void offs_scatter_kernel(
    const int* __restrict__ gcnt, const unsigned* __restrict__ ebin,
    int* __restrict__ offs, int* __restrict__ csr_src)
{
    __shared__ unsigned eb[BCAP];          // 49152 B
    __shared__ int hist[BRANGE];           // 6272 B
    __shared__ int bscan[NBKT];            // 512 B
    __shared__ int pscan[512];             // 2048 B
    const int b = blockIdx.x, t = threadIdx.x;
    const int cnt = gcnt[b];
    for (int i = t; i < cnt; i += 512)
        eb[i] = __builtin_nontemporal_load(&ebin[(size_t)b * BCAP + i]);
    for (int i = t; i < BRANGE; i += 512) hist[i] = 0;
    if (t < NBKT) bscan[t] = gcnt[t];
    __syncthreads();
    for (int i = t; i < cnt; i += 512)
        atomicAdd(&hist[eb[i] >> 18], 1);
    __syncthreads();
    // inclusive scan over the 128 bucket counts
    for (int off = 1; off < NBKT; off <<= 1) {
        const int u = (t >= off && t < NBKT) ? bscan[t - off] : 0;
        __syncthreads();
        if (t < NBKT) bscan[t] += u;
        __syncthreads();
    }
    const int bucketBase = (b == 0) ? 0 : bscan[b - 1];
    // per-thread chunk of 4 nodes, then 512-wide scan
    const int i0 = t * 4;
    const int h0v = (i0 + 0 < BRANGE) ? hist[i0 + 0] : 0;
    const int h1v = (i0 + 1 < BRANGE) ? hist[i0 + 1] : 0;
    const int h2v = (i0 + 2 < BRANGE) ? hist[i0 + 2] : 0;
    const int h3v = (i0 + 3 < BRANGE) ? hist[i0 + 3] : 0;
    const int ts = h0v + h1v + h2v + h3v;
    pscan[t] = ts;
    __syncthreads();
    for (int off = 1; off < 512; off <<= 1) {
        const int u = (t >= off) ? pscan[t - off] : 0;
        __syncthreads();
        pscan[t] += u;
        __syncthreads();
    }
    const int excl = pscan[t] - ts + bucketBase;
    const int r0 = b * BRANGE;
    // write offs + rewrite hist in-place as absolute cursors
    if (i0 + 0 < BRANGE) {
        if (r0 + i0 + 0 < N_NODES) offs[r0 + i0 + 0] = excl;
        hist[i0 + 0] = excl;
    }
    if (i0 + 1 < BRANGE) {
        if (r0 + i0 + 1 < N_NODES) offs[r0 + i0 + 1] = excl + h0v;
        hist[i0 + 1] = excl + h0v;
    }
    if (i0 + 2 < BRANGE) {
        if (r0 + i0 + 2 < N_NODES) offs[r0 + i0 + 2] = excl + h0v + h1v;
        hist[i0 + 2] = excl + h0v + h1v;
    }
    if (i0 + 3 < BRANGE) {
        if (r0 + i0 + 3 < N_NODES) offs[r0 + i0 + 3] = excl + h0v + h1v + h2v;
        hist[i0 + 3] = excl + h0v + h1v + h2v;
    }
    if (b == NBKT - 1 && t == 0) offs[N_NODES] = N_EDGES;
    __syncthreads();
    // scatter from LDS; cursors are absolute csr positions
    for (int i = t; i < cnt; i += 512) {
        const unsigned e = eb[i];
        const int pos = atomicAdd(&hist[e >> 18], 1);
        csr_src[pos] = (int)(e & 0x3FFFFu);
    }
}

// ===========================================================================
// Fused GIN layer. h accesses CACHED (h rows carry gather reuse). allLds
// branch removes the per-edge predicated csr[] load. 6 blocks/CU. POOL=true
// (last layer): pool directly from Ztmp via atomics, skip hout store.
// ===========================================================================
template<bool POOL>
__global__ __launch_bounds__(256, 6) void agg_mlp_kernel(
    const float* __restrict__ hin, float* __restrict__ hout,
    const int* __restrict__ offs, const int* __restrict__ csr,
    const int* __restrict__ batch, float* __restrict__ pooled,
    const unsigned short* __restrict__ wp1, const unsigned short* __restrict__ wp2,
    const float* __restrict__ b1, const float* __restrict__ g1,
    const float* __restrict__ bb1, const float* __restrict__ m1, const float* __restrict__ v1,
    const float* __restrict__ b2, const float* __restrict__ g2,
    const float* __restrict__ bb2, const float* __restrict__ m2, const float* __restrict__ v2)
{
    __shared__ __align__(16) float Ush[TILE_N * ZS];           // 17408 B union
    __shared__ int   OF[TILE_N + 1];
    __shared__ int   EIDX[ECAP];                               // 4 KB
    __shared__ float BNs[256];
    __shared__ int   GID[TILE_N];
    short* Abuf = (short*)Ush;
    float* Ztmp = Ush;
    const int t = threadIdx.x, lane = t & 63, w = t >> 6;
    const int sub = lane >> 4, cq = lane & 15;
    const int base = blockIdx.x * TILE_N;

    if (t < 64) {
        const float sa = g1[t] * rsqrtf(v1[t] + BN_EPS);
        BNs[t] = sa; BNs[64 + t] = b1[t] * sa + bb1[t] - m1[t] * sa;
        const float sb = g2[t] * rsqrtf(v2[t] + BN_EPS);
        BNs[128 + t] = sb; BNs[192 + t] = b2[t] * sb + bb2[t] - m2[t] * sb;
        if (POOL) GID[t] = batch[base + t];
    }
    if (t <= TILE_N) OF[t] = offs[base + t];
    const int segStart = offs[base];
    const int segEnd   = offs[base + TILE_N];
    for (int i = t; i < segEnd - segStart; i += 256)
        if (i < ECAP) EIDX[i] = csr[segStart + i];
    __syncthreads();

    // gather -> A-frag hi/lo writes (swizzled slots)
    // two chains (A,B) advance together: 8 independent loads per wait
    const float* __restrict__ hc = hin + cq * 4;
    const bool allLds = (segEnd - segStart) <= ECAP;   // true for ~all tiles

    auto gather_pass = [&](auto ldsTag) {
        constexpr bool LDSONLY = decltype(ldsTag)::value;
        #pragma unroll
        for (int pp = 0; pp < 2; pp++) {
            const int mlA = (pp * 2 + 0) * 4 + sub;
            const int mlB = (pp * 2 + 1) * 4 + sub;
            const int nlA = w * 16 + mlA, nlB = w * 16 + mlB;
            int eA = OF[nlA]; const int eA1 = OF[nlA + 1];
            int eB = OF[nlB]; const int eB1 = OF[nlB + 1];
            // clamp targets stay inside [segStart, segEnd): deg-0-safe
            const int eAm = (eA1 - 1 > segStart) ? eA1 - 1 : segStart;
            const int eBm = (eB1 - 1 > segStart) ? eB1 - 1 : segStart;
            f32x4 accA = *(const f32x4*)(hin + (size_t)(base + nlA) * HID + cq * 4);
            f32x4 accB = *(const f32x4*)(hin + (size_t)(base + nlB) * HID + cq * 4);
            while (eA < eA1 || eB < eB1) {
                int ia[4], ib[4];
                #pragma unroll
                for (int k = 0; k < 4; k++) {
                    const int ea = (eA + k < eAm) ? eA + k : eAm;
                    const int eb = (eB + k < eBm) ? eB + k : eBm;
                    const int la = ea - segStart, lb = eb - segStart;
                    if (LDSONLY) {
                        ia[k] = EIDX[la];
                        ib[k] = EIDX[lb];
                    } else {
                        ia[k] = (la < ECAP) ? EIDX[la] : csr[ea];
                        ib[k] = (lb < ECAP) ? EIDX[lb] : csr[eb];
                    }
                }
                f32x4 va[4], vb[4];
                #pragma unroll
                for (int k = 0; k < 4; k++) {
                    va[k] = *(const f32x4*)(hc + (size_t)ia[k] * HID);
                    vb[k] = *(const f32x4*)(hc + (size_t)ib[k] * HID);
                }
                #pragma unroll
                for (int k = 0; k < 4; k++) {
                    const float ma = (eA + k < eA1) ? 1.f : 0.f;
                    const float mb = (eB + k < eB1) ? 1.f : 0.f;
                    accA += va[k] * ma;
                    accB += vb[k] * mb;
                }
                eA += 4; eB += 4;
            }
            {
                uint2 hi, lo; cvt4(accA, hi, lo);
                const int s = cq >> 3, lc = mlA + 16 * ((cq >> 1) & 3), half = cq & 1;
                const int sl0 = ((w * 2 + s) * 2 + 0) * 64 + lc;
                const int sl1 = ((w * 2 + s) * 2 + 1) * 64 + lc;
                *(uint2*)&Abuf[SWZ(sl0) * 8 + half * 4] = hi;
                *(uint2*)&Abuf[SWZ(sl1) * 8 + half * 4] = lo;
            }
            {
                uint2 hi, lo; cvt4(accB, hi, lo);
                const int s = cq >> 3, lc = mlB + 16 * ((cq >> 1) & 3), half = cq & 1;
                const int sl0 = ((w * 2 + s) * 2 + 0) * 64 + lc;
                const int sl1 = ((w * 2 + s) * 2 + 1) * 64 + lc;
                *(uint2*)&Abuf[SWZ(sl0) * 8 + half * 4] = hi;
                *(uint2*)&Abuf[SWZ(sl1) * 8 + half * 4] = lo;
            }
        }
    };
    if (allLds) gather_pass(BoolC<true>{});
    else        gather_pass(BoolC<false>{});
    __syncthreads();

    const bf16x8* A = (const bf16x8*)Abuf;
    const int q = lane >> 4, c = lane & 15;

    // GEMM1
    {
        const bf16x8 a0h = A[SWZ(((w * 2 + 0) * 2 + 0) * 64 + lane)];
        const bf16x8 a0l = A[SWZ(((w * 2 + 0) * 2 + 1) * 64 + lane)];
        const bf16x8 a1h = A[SWZ(((w * 2 + 1) * 2 + 0) * 64 + lane)];
        const bf16x8 a1l = A[SWZ(((w * 2 + 1) * 2 + 1) * 64 + lane)];
        __syncthreads();    // frag reads done; Ztmp writes may alias Abuf
        const bf16x8* B = (const bf16x8*)wp1;
        #pragma unroll
        for (int ct = 0; ct < 4; ct++) {
            const bf16x8 b0h = B[(ct << 8) + lane];
            const bf16x8 b0l = B[(ct << 8) + 64 + lane];
            const bf16x8 b1h_ = B[(ct << 8) + 128 + lane];
            const bf16x8 b1l_ = B[(ct << 8) + 192 + lane];
            f32x4 acc = {0.f, 0.f, 0.f, 0.f};
            acc = MFMA16(a0h, b0h, acc);
            acc = MFMA16(a0h, b0l, acc);
            acc = MFMA16(a0l, b0h, acc);
            acc = MFMA16(a1h, b1h_, acc);
            acc = MFMA16(a1h, b1l_, acc);
            acc = MFMA16(a1l, b1h_, acc);
            const int n = ct * 16 + c;
            const float sc = BNs[n], sh = BNs[64 + n];
            #pragma unroll
            for (int r = 0; r < 4; r++)
                Ztmp[(w * 16 + q * 4 + r) * ZS + n] = fmaxf(acc[r] * sc + sh, 0.f);
        }
    }
    __syncthreads();    // Ztmp complete

    // re-split t1 into A-frags (register-staged: read all, barrier, write)
    {
        const int m = t >> 2;
        f32x4 vv[4];
        #pragma unroll
        for (int d = 0; d < 4; d++) {
            const int k4 = (t & 3) * 4 + d;
            vv[d] = *(const f32x4*)(&Ztmp[m * ZS + k4 * 4]);
        }
        __syncthreads();    // Ztmp reads done; A-frag writes may alias
        #pragma unroll
        for (int d = 0; d < 4; d++) {
            const int k4 = (t & 3) * 4 + d;
            uint2 hi, lo; cvt4(vv[d], hi, lo);
            const int s = k4 >> 3, lc = (m & 15) + 16 * ((k4 >> 1) & 3);
            const int half = k4 & 1, wm = m >> 4;
            const int sl0 = ((wm * 2 + s) * 2 + 0) * 64 + lc;
            const int sl1 = ((wm * 2 + s) * 2 + 1) * 64 + lc;
            *(uint2*)&Abuf[SWZ(sl0) * 8 + half * 4] = hi;
            *(uint2*)&Abuf[SWZ(sl1) * 8 + half * 4] = lo;
        }
    }
    __syncthreads();

    // GEMM2
    {
        const bf16x8 a0h = A[SWZ(((w * 2 + 0) * 2 + 0) * 64 + lane)];
        const bf16x8 a0l = A[SWZ(((w * 2 + 0) * 2 + 1) * 64 + lane)];
        const bf16x8 a1h = A[SWZ(((w * 2 + 1) * 2 + 0) * 64 + lane)];
        const bf16x8 a1l = A[SWZ(((w * 2 + 1) * 2 + 1) * 64 + lane)];
        __syncthreads();    // frag reads done; Ztmp writes may alias Abuf
        const bf16x8* B = (const bf16x8*)wp2;
        #pragma unroll
        for (int ct = 0; ct < 4; ct++) {
            const bf16x8 b0h = B[(ct << 8) + lane];
            const bf16x8 b0l = B[(ct << 8) + 64 + lane];
            const bf16x8 b1h_ = B[(ct << 8) + 128 + lane];
            const bf16x8 b1l_ = B[(ct << 8) + 192 + lane];
            f32x4 acc = {0.f, 0.f, 0.f, 0.f};
            acc = MFMA16(a0h, b0h, acc);
            acc = MFMA16(a0h, b0l, acc);
            acc = MFMA16(a0l, b0h, acc);
            acc = MFMA16(a1h, b1h_, acc);
            acc = MFMA16(a1h, b1l_, acc);
            acc = MFMA16(a1l, b1h_, acc);
            const int n = ct * 16 + c;
            const float sc = BNs[128 + n], sh = BNs[192 + n];
            #pragma unroll
            for (int r = 0; r < 4; r++)
                Ztmp[(w * 16 + q * 4 + r) * ZS + n] = fmaxf(acc[r] * sc + sh, 0.f);
        }
    }
    __syncthreads();

    if (POOL) {
        // pool directly from Ztmp: thread (c = t&63, rg = t>>6) run-sums its
        // 16 rows' column c grouped by graph id -> <=3 atomics per thread
        // into the L2-resident pooled[1024][64].
        const int cc = t & 63, rg = t >> 6;
        float run = 0.f;
        int cur = GID[rg * 16];
        #pragma unroll
        for (int r = 0; r < 16; r++) {
            const int row = rg * 16 + r;
            const int g = GID[row];
            if (g != cur) {
                atomicAdd(&pooled[(size_t)cur * HID + cc], run);
                run = 0.f; cur = g;
            }
            run += Ztmp[row * ZS + cc];
        }
        atomicAdd(&pooled[(size_t)cur * HID + cc], run);
    } else {
        #pragma unroll
        for (int i = 0; i < 4; i++) {
            const int idx = t + i * 256, n = idx >> 4, k4 = idx & 15;
            *(f32x4*)(hout + (size_t)(base + n) * HID + k4 * 4) =
                *(const f32x4*)(&Ztmp[n * ZS + k4 * 4]);
        }
    }
}

// ===========================================================================
// Classifier: cnt derived from goffs.
// ===========================================================================
__global__ __launch_bounds__(64) void cls_kernel(
    const float* __restrict__ pooled, const int* __restrict__ goffs,
    const float* __restrict__ w1, const float* __restrict__ b1,
    const float* __restrict__ w2, const float* __restrict__ b2,
    float* __restrict__ out)
{
    const int g = blockIdx.x;
    const int lane = threadIdx.x;
    const float c = (float)(goffs[g + 1] - goffs[g]);
    const float p = pooled[(size_t)g * HID + lane] / fmaxf(c, 1.f);
    float acc = (lane < 32) ? b1[lane] : 0.f;
    #pragma unroll
    for (int k = 0; k < 64; k++) {
        const float pk = __shfl(p, k, 64);
        if (lane < 32) acc += pk * w1[k * 32 + lane];
    }
    const float hmid = fmaxf(acc, 0.f);
    float acc2 = (lane < NCLS) ? b2[lane] : 0.f;
    #pragma unroll
    for (int k = 0; k < 32; k++) {
        const float hk = __shfl(hmid, k, 64);
        if (lane < NCLS) acc2 += hk * w2[k * NCLS + lane];
    }
    if (lane < NCLS) out[(size_t)g * NCLS + lane] = acc2;
}

// ===========================================================================
extern "C" void kernel_launch(void* const* d_in, const int* in_sizes, int n_in,
                              void* d_out, int out_size, void* d_ws, size_t ws_size,
                              hipStream_t stream) {
    const float* x     = (const float*)d_in[0];
    const int*   ei    = (const int*)d_in[1];
    const int*   batch = (const int*)d_in[2];
    const float* emb_w = (const float*)d_in[3];
    const float* emb_b = (const float*)d_in[4];
    const float* ibn_g = (const float*)d_in[5];
    const float* ibn_b = (const float*)d_in[6];
    const float* ibn_m = (const float*)d_in[7];
    const float* ibn_v = (const float*)d_in[8];
    const float* fc1_w = (const float*)d_in[9];
    const float* fc1_b = (const float*)d_in[10];
    const float* mbn_g = (const float*)d_in[11];
    const float* mbn_b = (const float*)d_in[12];
    const float* mbn_m = (const float*)d_in[13];
    const float* mbn_v = (const float*)d_in[14];
    const float* fc2_w = (const float*)d_in[15];
    const float* fc2_b = (const float*)d_in[16];
    const float* obn_g = (const float*)d_in[17];
    const float* obn_b = (const float*)d_in[18];
    const float* obn_m = (const float*)d_in[19];
    const float* obn_v = (const float*)d_in[20];
    const float* cls1w = (const float*)d_in[21];
    const float* cls1b = (const float*)d_in[22];
    const float* cls2w = (const float*)d_in[23];
    const float* cls2b = (const float*)d_in[24];

    float* h0     = (float*)d_ws;
    float* h1     = h0 + (size_t)N_NODES * HID;
    float* pooled = h1 + (size_t)N_NODES * HID;
    float* cnt    = pooled + NGRAPH * HID;            // unused (layout keep)
    int*   deg    = (int*)(cnt + NGRAPH);             // unused (layout keep)
    int*   offs   = deg + N_NODES;
    int*   bsum   = offs + (N_NODES + 1);             // unused
    int*   boff   = bsum + 256;                       // unused
    int*   csr    = boff + 256;
    unsigned short* wpe = (unsigned short*)(csr + N_EDGES);   // 16384
    unsigned short* wpf = wpe + 16384;                        // 49152
    int*   goffs  = (int*)(wpf + 49152);                      // NGRAPH+1
    int*   gcnt   = goffs + (NGRAPH + 1);                     // NBKT
    // ebin (packed u32) aliases h1: consumed by offs_scatter BEFORE agg1
    // writes h1. 128*12288*4 B = 6.3 MB << 51.2 MB. (h0 now busy with the
    // concurrent embed in csr_embed_kernel.)
    unsigned* ebin = (unsigned*)h1;

    const int* src = ei;
    const int* dst = ei + N_EDGES;

    // weight prep + graph offsets + gcnt zero + pooled zero (all fused)
    setup_kernel<<<325, 256, 0, stream>>>(emb_w, wpe, fc1_w, fc2_w, wpf,
                                          batch, goffs, gcnt, pooled);

    // fused: edge binning (293 blocks) runs concurrently with embed (3125)
    const int gemm_blocks = N_NODES / TILE_N;   // 3125
    csr_embed_kernel<<<NB_BIN + gemm_blocks, 256, 0, stream>>>(
        src, dst, gcnt, ebin,
        x, wpe, emb_b, ibn_g, ibn_b, ibn_m, ibn_v, h0);

    // fused offs + scatter (one ebin read, LDS-staged)
    offs_scatter_kernel<<<NBKT, 512, 0, stream>>>(gcnt, ebin, offs, csr);

    const float* hin = h0;
    float* hout = h1;
    for (int i = 0; i < 3; i++) {
        if (i < 2)
            agg_mlp_kernel<false><<<gemm_blocks, 256, 0, stream>>>(
                hin, hout, offs, csr, batch, pooled,
                wpf + (size_t)(i * 2 + 0) * 8192, wpf + (size_t)(i * 2 + 1) * 8192,
                fc1_b + i * HID, mbn_g + i * HID, mbn_b + i * HID, mbn_m + i * HID, mbn_v + i * HID,
                fc2_b + i * HID, obn_g + i * HID, obn_b + i * HID, obn_m + i * HID, obn_v + i * HID);
        else
            agg_mlp_kernel<true><<<gemm_blocks, 256, 0, stream>>>(
                hin, hout, offs, csr, batch, pooled,
                wpf + (size_t)(i * 2 + 0) * 8192, wpf + (size_t)(i * 2 + 1) * 8192,
                fc1_b + i * HID, mbn_g + i * HID, mbn_b + i * HID, mbn_m + i * HID, mbn_v + i * HID,
                fc2_b + i * HID, obn_g + i * HID, obn_b + i * HID, obn_m + i * HID, obn_v + i * HID);
        const float* tmp = hin; hin = hout; hout = (float*)tmp;
    }

    cls_kernel<<<NGRAPH, 64, 0, stream>>>(pooled, goffs, cls1w, cls1b, cls2w, cls2b,
                                          (float*)d_out);
}

// Round 9
// 458.680 us; speedup vs baseline: 1.1150x; 1.0106x over previous
//
#include <hip/hip_runtime.h>
#include <hip/hip_bf16.h>

#define N_NODES 200000
#define N_EDGES 1200000
#define IN_DIM  128
#define HID     64
#define NGRAPH  1024
#define NCLS    6
#define BN_EPS  1e-5f

#define TILE_N   64
#define ZS       68          // Ztmp row stride (floats); 272B = 17 banks shift, 2-way max
#define ECAP     1024

// ---- binned CSR build ----
#define NBKT   128           // dst-range buckets
#define BRANGE 1568          // nodes per bucket (128*1568 = 200704 >= N)
#define BCAP   12288         // per-bucket edge capacity (mean 9408, sigma ~97)
#define EPB    4096          // edges per bin block
#define NB_BIN ((N_EDGES + EPB - 1) / EPB)   // 293
#define NB_SETUP 325         // setup blocks before the bin range
// packed ebin entry: src (18b) | dstLocal (11b) << 18

// 16B-slot XOR swizzle for A-frag LDS
#define SWZ(s) ((s) ^ (((s) >> 4) & 3))

typedef short bf16x8 __attribute__((ext_vector_type(8)));
typedef float f32x4  __attribute__((ext_vector_type(4)));
#define MFMA16(a,b,c) __builtin_amdgcn_mfma_f32_16x16x32_bf16((a),(b),(c),0,0,0)

template<bool V> struct BoolC { static constexpr bool value = V; };

__device__ __forceinline__ unsigned short f2bf(float f) {
    union { __hip_bfloat16 h; unsigned short u; } v; v.h = __float2bfloat16(f); return v.u;
}
__device__ __forceinline__ float bfbits2f(unsigned short u) {
    union { unsigned int i; float f; } v; v.i = ((unsigned int)u) << 16; return v.f;
}
// f32x4 -> (hi bf16x4, lo bf16x4) packed as uint2 each
__device__ __forceinline__ void cvt4(const f32x4& x, uint2& hi, uint2& lo) {
    const unsigned short h0 = f2bf(x[0]), h1 = f2bf(x[1]), h2 = f2bf(x[2]), h3 = f2bf(x[3]);
    hi.x = (unsigned)h0 | ((unsigned)h1 << 16);
    hi.y = (unsigned)h2 | ((unsigned)h3 << 16);
    const unsigned short l0 = f2bf(x[0] - bfbits2f(h0)), l1 = f2bf(x[1] - bfbits2f(h1));
    const unsigned short l2 = f2bf(x[2] - bfbits2f(h2)), l3 = f2bf(x[3] - bfbits2f(h3));
    lo.x = (unsigned)l0 | ((unsigned)l1 << 16);
    lo.y = (unsigned)l2 | ((unsigned)l3 << 16);
}

// ===========================================================================
// Setup + bin kernel. Blocks 0..63 prep_emb, 64..255 prep_fc, 256..260
// graph_offs, 261..324 pooled-zero, 325..617 edge binning. The trivial setup
// blocks finish immediately; bin gets the whole machine (r7's bin-inside-
// embed fusion dragged embed 44->74 us by mixing workloads). gcnt zeroed by
// a preceding 512 B memset (in-kernel zeroing would race the bin blocks).
// ===========================================================================
__global__ __launch_bounds__(256) void setup_bin_kernel(
    const float* __restrict__ emb_w, unsigned short* __restrict__ wpe,
    const float* __restrict__ fc1, const float* __restrict__ fc2,
    unsigned short* __restrict__ wpf,
    const int* __restrict__ batch, int* __restrict__ goffs,
    int* __restrict__ gcnt, float* __restrict__ pooled,
    const int* __restrict__ src, const int* __restrict__ dst,
    unsigned* __restrict__ ebin)
{
    __shared__ int hist[NBKT];
    __shared__ int basis[NBKT];
    const int b = blockIdx.x, t = threadIdx.x;
    if (b >= NB_SETUP) {
        // ---- bin path ----
        const int base = (b - NB_SETUP) * EPB;
        if (t < NBKT) hist[t] = 0;
        __syncthreads();
        int sv[16], dv[16];
        #pragma unroll
        for (int i = 0; i < 16; i++) {
            const int e = base + t + i * 256;
            if (e < N_EDGES) {
                sv[i] = __builtin_nontemporal_load(&src[e]);
                dv[i] = __builtin_nontemporal_load(&dst[e]);
                atomicAdd(&hist[dv[i] / BRANGE], 1);
            } else { sv[i] = -1; dv[i] = -1; }
        }
        __syncthreads();
        if (t < NBKT) { basis[t] = atomicAdd(&gcnt[t], hist[t]); hist[t] = 0; }
        __syncthreads();
        #pragma unroll
        for (int i = 0; i < 16; i++) {
            if (dv[i] >= 0) {
                const int bb = dv[i] / BRANGE;
                const int dl = dv[i] - bb * BRANGE;
                const int pos = basis[bb] + atomicAdd(&hist[bb], 1);
                __builtin_nontemporal_store(
                    (unsigned)sv[i] | ((unsigned)dl << 18),
                    &ebin[(size_t)bb * BCAP + pos]);
            }
        }
        return;
    }
    if (b < 64) {
        const int idx = b * 256 + t;                     // [ct2][s2][p1][l6][j3]
        const int j = idx & 7, l = (idx >> 3) & 63;
        const int plane = (idx >> 9) & 1, s = (idx >> 10) & 3, ct = (idx >> 12) & 3;
        const int n = ct * 16 + (l & 15);
        const int k = s * 32 + (l >> 4) * 8 + j;
        const float f = emb_w[k * 64 + n];
        const unsigned short hb = f2bf(f);
        wpe[idx] = plane ? f2bf(f - bfbits2f(hb)) : hb;
    } else if (b < 256) {
        const int idx = (b - 64) * 256 + t;              // [layer][g][ct2][s1][p1][l6][j3]
        const int j = idx & 7, l = (idx >> 3) & 63;
        const int plane = (idx >> 9) & 1, s = (idx >> 10) & 1, ct = (idx >> 11) & 3;
        const int g = (idx >> 13) & 1, layer = idx >> 14;
        const int n = ct * 16 + (l & 15);
        const int k = s * 32 + (l >> 4) * 8 + j;
        const float* W = g ? fc2 : fc1;
        const float f = W[(layer * 64 + k) * 64 + n];
        const unsigned short hb = f2bf(f);
        wpf[idx] = plane ? f2bf(f - bfbits2f(hb)) : hb;
    } else if (b < 261) {
        const int g = (b - 256) * 256 + t;
        if (g > NGRAPH) return;
        if (g == NGRAPH) { goffs[NGRAPH] = N_NODES; return; }
        int lo = 0, hi = N_NODES;
        while (lo < hi) {
            const int mid = (lo + hi) >> 1;
            if (batch[mid] < g) lo = mid + 1; else hi = mid;
        }
        goffs[g] = lo;
    } else {
        const int idx = (b - 261) * 256 + t;             // 16384 float4s
        const f32x4 z = {0.f, 0.f, 0.f, 0.f};
        *(f32x4*)(pooled + (size_t)idx * 4) = z;
    }
}

// ===========================================================================
// Embed (standalone again): h0 = relu(bn(x @ W + b)) via split-bf16 MFMA.
// x NT-read (true stream); h0 store NORMAL (layer-1 gather prefill).
// ===========================================================================
__global__ __launch_bounds__(256) void embed_kernel(
    const float* __restrict__ x, const unsigned short* __restrict__ wpe,
    const float* __restrict__ bias,
    const float* __restrict__ bn_g, const float* __restrict__ bn_b,
    const float* __restrict__ bn_m, const float* __restrict__ bn_v,
    float* __restrict__ h)
{
    __shared__ __align__(16) float Ush[8192];                  // 32 KB union
    __shared__ float BNs[128];
    short* Abuf = (short*)Ush;
    float* Ztmp = Ush;
    const int t = threadIdx.x, lane = t & 63, w = t >> 6;
    const int base = blockIdx.x * TILE_N;

    if (t < 64) {
        const float s = bn_g[t] * rsqrtf(bn_v[t] + BN_EPS);
        BNs[t] = s;
        BNs[64 + t] = bias[t] * s + bn_b[t] - bn_m[t] * s;
    }
    // stage + hi/lo convert x tile into A-frag order (swizzled slots)
    #pragma unroll
    for (int i = 0; i < 8; i++) {
        const int idx = t + i * 256;                 // 0..2047
        const int n = idx >> 5, k4 = idx & 31;
        const f32x4 v = __builtin_nontemporal_load(
            (const f32x4*)(x + (size_t)(base + n) * IN_DIM + k4 * 4));
        uint2 hi, lo; cvt4(v, hi, lo);
        const int s = k4 >> 3, lc = (n & 15) + 16 * ((k4 >> 1) & 3);
        const int half = k4 & 1, wm = n >> 4;
        const int sl0 = ((wm * 4 + s) * 2 + 0) * 64 + lc;
        const int sl1 = ((wm * 4 + s) * 2 + 1) * 64 + lc;
        *(uint2*)&Abuf[SWZ(sl0) * 8 + half * 4] = hi;
        *(uint2*)&Abuf[SWZ(sl1) * 8 + half * 4] = lo;
    }
    __syncthreads();

    const bf16x8* A = (const bf16x8*)Abuf;
    const bf16x8* B = (const bf16x8*)wpe;
    bf16x8 ah[4], al[4];
    #pragma unroll
    for (int s = 0; s < 4; s++) {
        ah[s] = A[SWZ(((w * 4 + s) * 2 + 0) * 64 + lane)];
        al[s] = A[SWZ(((w * 4 + s) * 2 + 1) * 64 + lane)];
    }
    __syncthreads();    // all frag reads done; Ztmp may overwrite Abuf
    const int q = lane >> 4, c = lane & 15;
    #pragma unroll
    for (int ct = 0; ct < 4; ct++) {
        f32x4 acc = {0.f, 0.f, 0.f, 0.f};
        #pragma unroll
        for (int s = 0; s < 4; s++) {
            const bf16x8 bh = B[(ct << 9) + (s << 7) + lane];
            const bf16x8 bl = B[(ct << 9) + (s << 7) + 64 + lane];
            acc = MFMA16(ah[s], bh, acc);
            acc = MFMA16(ah[s], bl, acc);
            acc = MFMA16(al[s], bh, acc);
        }
        const int n = ct * 16 + c;
        const float sc = BNs[n], sh = BNs[64 + n];
        #pragma unroll
        for (int r = 0; r < 4; r++)
            Ztmp[(w * 16 + q * 4 + r) * ZS + n] = fmaxf(acc[r] * sc + sh, 0.f);
    }
    __syncthreads();
    #pragma unroll
    for (int i = 0; i < 4; i++) {
        const int idx = t + i * 256, n = idx >> 4, k4 = idx & 15;
        *(f32x4*)(h + (size_t)(base + n) * HID + k4 * 4) =
            *(const f32x4*)(&Ztmp[n * ZS + k4 * 4]);
    }
}

// ===========================================================================
// Fused offs+scatter: one block per bucket. Stage packed edges in LDS (one
// ebin read instead of two), histogram, 2-level scan -> offs, rewrite hist
// as absolute cursors, scatter to csr straight from LDS.
// ===========================================================================
__global__ __launch_bounds__(512) void offs_scatter_kernel(
    const int* __restrict__ gcnt, const unsigned* __restrict__ ebin,
    int* __restrict__ offs, int* __restrict__ csr_src)
{
    __shared__ unsigned eb[BCAP];          // 49152 B
    __shared__ int hist[BRANGE];           // 6272 B
    __shared__ int bscan[NBKT];            // 512 B
    __shared__ int pscan[512];             // 2048 B
    const int b = blockIdx.x, t = threadIdx.x;
    const int cnt = gcnt[b];
    for (int i = t; i < cnt; i += 512)
        eb[i] = __builtin_nontemporal_load(&ebin[(size_t)b * BCAP + i]);
    for (int i = t; i < BRANGE; i += 512) hist[i] = 0;
    if (t < NBKT) bscan[t] = gcnt[t];
    __syncthreads();
    for (int i = t; i < cnt; i += 512)
        atomicAdd(&hist[eb[i] >> 18], 1);
    __syncthreads();
    // inclusive scan over the 128 bucket counts
    for (int off = 1; off < NBKT; off <<= 1) {
        const int u = (t >= off && t < NBKT) ? bscan[t - off] : 0;
        __syncthreads();
        if (t < NBKT) bscan[t] += u;
        __syncthreads();
    }
    const int bucketBase = (b == 0) ? 0 : bscan[b - 1];
    // per-thread chunk of 4 nodes, then 512-wide scan
    const int i0 = t * 4;
    const int h0v = (i0 + 0 < BRANGE) ? hist[i0 + 0] : 0;
    const int h1v = (i0 + 1 < BRANGE) ? hist[i0 + 1] : 0;
    const int h2v = (i0 + 2 < BRANGE) ? hist[i0 + 2] : 0;
    const int h3v = (i0 + 3 < BRANGE) ? hist[i0 + 3] : 0;
    const int ts = h0v + h1v + h2v + h3v;
    pscan[t] = ts;
    __syncthreads();
    for (int off = 1; off < 512; off <<= 1) {
        const int u = (t >= off) ? pscan[t - off] : 0;
        __syncthreads();
        pscan[t] += u;
        __syncthreads();
    }
    const int excl = pscan[t] - ts + bucketBase;
    const int r0 = b * BRANGE;
    // write offs + rewrite hist in-place as absolute cursors
    if (i0 + 0 < BRANGE) {
        if (r0 + i0 + 0 < N_NODES) offs[r0 + i0 + 0] = excl;
        hist[i0 + 0] = excl;
    }
    if (i0 + 1 < BRANGE) {
        if (r0 + i0 + 1 < N_NODES) offs[r0 + i0 + 1] = excl + h0v;
        hist[i0 + 1] = excl + h0v;
    }
    if (i0 + 2 < BRANGE) {
        if (r0 + i0 + 2 < N_NODES) offs[r0 + i0 + 2] = excl + h0v + h1v;
        hist[i0 + 2] = excl + h0v + h1v;
    }
    if (i0 + 3 < BRANGE) {
        if (r0 + i0 + 3 < N_NODES) offs[r0 + i0 + 3] = excl + h0v + h1v + h2v;
        hist[i0 + 3] = excl + h0v + h1v + h2v;
    }
    if (b == NBKT - 1 && t == 0) offs[N_NODES] = N_EDGES;
    __syncthreads();
    // scatter from LDS; cursors are absolute csr positions
    for (int i = t; i < cnt; i += 512) {
        const unsigned e = eb[i];
        const int pos = atomicAdd(&hist[e >> 18], 1);
        csr_src[pos] = (int)(e & 0x3FFFFu);
    }
}

// ===========================================================================
// Fused GIN layer. h accesses CACHED (h rows carry gather reuse). allLds
// branch removes the per-edge predicated csr[] load. 6 blocks/CU. POOL=true
// (last layer): pool directly from Ztmp via atomics, skip hout store.
// ===========================================================================
template<bool POOL>
__global__ __launch_bounds__(256, 6) void agg_mlp_kernel(
    const float* __restrict__ hin, float* __restrict__ hout,
    const int* __restrict__ offs, const int* __restrict__ csr,
    const int* __restrict__ batch, float* __restrict__ pooled,
    const unsigned short* __restrict__ wp1, const unsigned short* __restrict__ wp2,
    const float* __restrict__ b1, const float* __restrict__ g1,
    const float* __restrict__ bb1, const float* __restrict__ m1, const float* __restrict__ v1,
    const float* __restrict__ b2, const float* __restrict__ g2,
    const float* __restrict__ bb2, const float* __restrict__ m2, const float* __restrict__ v2)
{
    __shared__ __align__(16) float Ush[TILE_N * ZS];           // 17408 B union
    __shared__ int   OF[TILE_N + 1];
    __shared__ int   EIDX[ECAP];                               // 4 KB
    __shared__ float BNs[256];
    __shared__ int   GID[TILE_N];
    short* Abuf = (short*)Ush;
    float* Ztmp = Ush;
    const int t = threadIdx.x, lane = t & 63, w = t >> 6;
    const int sub = lane >> 4, cq = lane & 15;
    const int base = blockIdx.x * TILE_N;

    if (t < 64) {
        const float sa = g1[t] * rsqrtf(v1[t] + BN_EPS);
        BNs[t] = sa; BNs[64 + t] = b1[t] * sa + bb1[t] - m1[t] * sa;
        const float sb = g2[t] * rsqrtf(v2[t] + BN_EPS);
        BNs[128 + t] = sb; BNs[192 + t] = b2[t] * sb + bb2[t] - m2[t] * sb;
        if (POOL) GID[t] = batch[base + t];
    }
    if (t <= TILE_N) OF[t] = offs[base + t];
    const int segStart = offs[base];
    const int segEnd   = offs[base + TILE_N];
    for (int i = t; i < segEnd - segStart; i += 256)
        if (i < ECAP) EIDX[i] = csr[segStart + i];
    __syncthreads();

    // gather -> A-frag hi/lo writes (swizzled slots)
    // two chains (A,B) advance together: 8 independent loads per wait
    const float* __restrict__ hc = hin + cq * 4;
    const bool allLds = (segEnd - segStart) <= ECAP;   // true for ~all tiles

    auto gather_pass = [&](auto ldsTag) {
        constexpr bool LDSONLY = decltype(ldsTag)::value;
        #pragma unroll
        for (int pp = 0; pp < 2; pp++) {
            const int mlA = (pp * 2 + 0) * 4 + sub;
            const int mlB = (pp * 2 + 1) * 4 + sub;
            const int nlA = w * 16 + mlA, nlB = w * 16 + mlB;
            int eA = OF[nlA]; const int eA1 = OF[nlA + 1];
            int eB = OF[nlB]; const int eB1 = OF[nlB + 1];
            // clamp targets stay inside [segStart, segEnd): deg-0-safe
            const int eAm = (eA1 - 1 > segStart) ? eA1 - 1 : segStart;
            const int eBm = (eB1 - 1 > segStart) ? eB1 - 1 : segStart;
            f32x4 accA = *(const f32x4*)(hin + (size_t)(base + nlA) * HID + cq * 4);
            f32x4 accB = *(const f32x4*)(hin + (size_t)(base + nlB) * HID + cq * 4);
            while (eA < eA1 || eB < eB1) {
                int ia[4], ib[4];
                #pragma unroll
                for (int k = 0; k < 4; k++) {
                    const int ea = (eA + k < eAm) ? eA + k : eAm;
                    const int eb = (eB + k < eBm) ? eB + k : eBm;
                    const int la = ea - segStart, lb = eb - segStart;
                    if (LDSONLY) {
                        ia[k] = EIDX[la];
                        ib[k] = EIDX[lb];
                    } else {
                        ia[k] = (la < ECAP) ? EIDX[la] : csr[ea];
                        ib[k] = (lb < ECAP) ? EIDX[lb] : csr[eb];
                    }
                }
                f32x4 va[4], vb[4];
                #pragma unroll
                for (int k = 0; k < 4; k++) {
                    va[k] = *(const f32x4*)(hc + (size_t)ia[k] * HID);
                    vb[k] = *(const f32x4*)(hc + (size_t)ib[k] * HID);
                }
                #pragma unroll
                for (int k = 0; k < 4; k++) {
                    const float ma = (eA + k < eA1) ? 1.f : 0.f;
                    const float mb = (eB + k < eB1) ? 1.f : 0.f;
                    accA += va[k] * ma;
                    accB += vb[k] * mb;
                }
                eA += 4; eB += 4;
            }
            {
                uint2 hi, lo; cvt4(accA, hi, lo);
                const int s = cq >> 3, lc = mlA + 16 * ((cq >> 1) & 3), half = cq & 1;
                const int sl0 = ((w * 2 + s) * 2 + 0) * 64 + lc;
                const int sl1 = ((w * 2 + s) * 2 + 1) * 64 + lc;
                *(uint2*)&Abuf[SWZ(sl0) * 8 + half * 4] = hi;
                *(uint2*)&Abuf[SWZ(sl1) * 8 + half * 4] = lo;
            }
            {
                uint2 hi, lo; cvt4(accB, hi, lo);
                const int s = cq >> 3, lc = mlB + 16 * ((cq >> 1) & 3), half = cq & 1;
                const int sl0 = ((w * 2 + s) * 2 + 0) * 64 + lc;
                const int sl1 = ((w * 2 + s) * 2 + 1) * 64 + lc;
                *(uint2*)&Abuf[SWZ(sl0) * 8 + half * 4] = hi;
                *(uint2*)&Abuf[SWZ(sl1) * 8 + half * 4] = lo;
            }
        }
    };
    if (allLds) gather_pass(BoolC<true>{});
    else        gather_pass(BoolC<false>{});
    __syncthreads();

    const bf16x8* A = (const bf16x8*)Abuf;
    const int q = lane >> 4, c = lane & 15;

    // GEMM1
    {
        const bf16x8 a0h = A[SWZ(((w * 2 + 0) * 2 + 0) * 64 + lane)];
        const bf16x8 a0l = A[SWZ(((w * 2 + 0) * 2 + 1) * 64 + lane)];
        const bf16x8 a1h = A[SWZ(((w * 2 + 1) * 2 + 0) * 64 + lane)];
        const bf16x8 a1l = A[SWZ(((w * 2 + 1) * 2 + 1) * 64 + lane)];
        __syncthreads();    // frag reads done; Ztmp writes may alias Abuf
        const bf16x8* B = (const bf16x8*)wp1;
        #pragma unroll
        for (int ct = 0; ct < 4; ct++) {
            const bf16x8 b0h = B[(ct << 8) + lane];
            const bf16x8 b0l = B[(ct << 8) + 64 + lane];
            const bf16x8 b1h_ = B[(ct << 8) + 128 + lane];
            const bf16x8 b1l_ = B[(ct << 8) + 192 + lane];
            f32x4 acc = {0.f, 0.f, 0.f, 0.f};
            acc = MFMA16(a0h, b0h, acc);
            acc = MFMA16(a0h, b0l, acc);
            acc = MFMA16(a0l, b0h, acc);
            acc = MFMA16(a1h, b1h_, acc);
            acc = MFMA16(a1h, b1l_, acc);
            acc = MFMA16(a1l, b1h_, acc);
            const int n = ct * 16 + c;
            const float sc = BNs[n], sh = BNs[64 + n];
            #pragma unroll
            for (int r = 0; r < 4; r++)
                Ztmp[(w * 16 + q * 4 + r) * ZS + n] = fmaxf(acc[r] * sc + sh, 0.f);
        }
    }
    __syncthreads();    // Ztmp complete

    // re-split t1 into A-frags (register-staged: read all, barrier, write)
    {
        const int m = t >> 2;
        f32x4 vv[4];
        #pragma unroll
        for (int d = 0; d < 4; d++) {
            const int k4 = (t & 3) * 4 + d;
            vv[d] = *(const f32x4*)(&Ztmp[m * ZS + k4 * 4]);
        }
        __syncthreads();    // Ztmp reads done; A-frag writes may alias
        #pragma unroll
        for (int d = 0; d < 4; d++) {
            const int k4 = (t & 3) * 4 + d;
            uint2 hi, lo; cvt4(vv[d], hi, lo);
            const int s = k4 >> 3, lc = (m & 15) + 16 * ((k4 >> 1) & 3);
            const int half = k4 & 1, wm = m >> 4;
            const int sl0 = ((wm * 2 + s) * 2 + 0) * 64 + lc;
            const int sl1 = ((wm * 2 + s) * 2 + 1) * 64 + lc;
            *(uint2*)&Abuf[SWZ(sl0) * 8 + half * 4] = hi;
            *(uint2*)&Abuf[SWZ(sl1) * 8 + half * 4] = lo;
        }
    }
    __syncthreads();

    // GEMM2
    {
        const bf16x8 a0h = A[SWZ(((w * 2 + 0) * 2 + 0) * 64 + lane)];
        const bf16x8 a0l = A[SWZ(((w * 2 + 0) * 2 + 1) * 64 + lane)];
        const bf16x8 a1h = A[SWZ(((w * 2 + 1) * 2 + 0) * 64 + lane)];
        const bf16x8 a1l = A[SWZ(((w * 2 + 1) * 2 + 1) * 64 + lane)];
        __syncthreads();    // frag reads done; Ztmp writes may alias Abuf
        const bf16x8* B = (const bf16x8*)wp2;
        #pragma unroll
        for (int ct = 0; ct < 4; ct++) {
            const bf16x8 b0h = B[(ct << 8) + lane];
            const bf16x8 b0l = B[(ct << 8) + 64 + lane];
            const bf16x8 b1h_ = B[(ct << 8) + 128 + lane];
            const bf16x8 b1l_ = B[(ct << 8) + 192 + lane];
            f32x4 acc = {0.f, 0.f, 0.f, 0.f};
            acc = MFMA16(a0h, b0h, acc);
            acc = MFMA16(a0h, b0l, acc);
            acc = MFMA16(a0l, b0h, acc);
            acc = MFMA16(a1h, b1h_, acc);
            acc = MFMA16(a1h, b1l_, acc);
            acc = MFMA16(a1l, b1h_, acc);
            const int n = ct * 16 + c;
            const float sc = BNs[128 + n], sh = BNs[192 + n];
            #pragma unroll
            for (int r = 0; r < 4; r++)
                Ztmp[(w * 16 + q * 4 + r) * ZS + n] = fmaxf(acc[r] * sc + sh, 0.f);
        }
    }
    __syncthreads();

    if (POOL) {
        // pool directly from Ztmp: thread (c = t&63, rg = t>>6) run-sums its
        // 16 rows' column c grouped by graph id -> <=3 atomics per thread
        // into the L2-resident pooled[1024][64].
        const int cc = t & 63, rg = t >> 6;
        float run = 0.f;
        int cur = GID[rg * 16];
        #pragma unroll
        for (int r = 0; r < 16; r++) {
            const int row = rg * 16 + r;
            const int g = GID[row];
            if (g != cur) {
                atomicAdd(&pooled[(size_t)cur * HID + cc], run);
                run = 0.f; cur = g;
            }
            run += Ztmp[row * ZS + cc];
        }
        atomicAdd(&pooled[(size_t)cur * HID + cc], run);
    } else {
        #pragma unroll
        for (int i = 0; i < 4; i++) {
            const int idx = t + i * 256, n = idx >> 4, k4 = idx & 15;
            *(f32x4*)(hout + (size_t)(base + n) * HID + k4 * 4) =
                *(const f32x4*)(&Ztmp[n * ZS + k4 * 4]);
        }
    }
}

// ===========================================================================
// Classifier: cnt derived from goffs.
// ===========================================================================
__global__ __launch_bounds__(64) void cls_kernel(
    const float* __restrict__ pooled, const int* __restrict__ goffs,
    const float* __restrict__ w1, const float* __restrict__ b1,
    const float* __restrict__ w2, const float* __restrict__ b2,
    float* __restrict__ out)
{
    const int g = blockIdx.x;
    const int lane = threadIdx.x;
    const float c = (float)(goffs[g + 1] - goffs[g]);
    const float p = pooled[(size_t)g * HID + lane] / fmaxf(c, 1.f);
    float acc = (lane < 32) ? b1[lane] : 0.f;
    #pragma unroll
    for (int k = 0; k < 64; k++) {
        const float pk = __shfl(p, k, 64);
        if (lane < 32) acc += pk * w1[k * 32 + lane];
    }
    const float hmid = fmaxf(acc, 0.f);
    float acc2 = (lane < NCLS) ? b2[lane] : 0.f;
    #pragma unroll
    for (int k = 0; k < 32; k++) {
        const float hk = __shfl(hmid, k, 64);
        if (lane < NCLS) acc2 += hk * w2[k * NCLS + lane];
    }
    if (lane < NCLS) out[(size_t)g * NCLS + lane] = acc2;
}

// ===========================================================================
extern "C" void kernel_launch(void* const* d_in, const int* in_sizes, int n_in,
                              void* d_out, int out_size, void* d_ws, size_t ws_size,
                              hipStream_t stream) {
    const float* x     = (const float*)d_in[0];
    const int*   ei    = (const int*)d_in[1];
    const int*   batch = (const int*)d_in[2];
    const float* emb_w = (const float*)d_in[3];
    const float* emb_b = (const float*)d_in[4];
    const float* ibn_g = (const float*)d_in[5];
    const float* ibn_b = (const float*)d_in[6];
    const float* ibn_m = (const float*)d_in[7];
    const float* ibn_v = (const float*)d_in[8];
    const float* fc1_w = (const float*)d_in[9];
    const float* fc1_b = (const float*)d_in[10];
    const float* mbn_g = (const float*)d_in[11];
    const float* mbn_b = (const float*)d_in[12];
    const float* mbn_m = (const float*)d_in[13];
    const float* mbn_v = (const float*)d_in[14];
    const float* fc2_w = (const float*)d_in[15];
    const float* fc2_b = (const float*)d_in[16];
    const float* obn_g = (const float*)d_in[17];
    const float* obn_b = (const float*)d_in[18];
    const float* obn_m = (const float*)d_in[19];
    const float* obn_v = (const float*)d_in[20];
    const float* cls1w = (const float*)d_in[21];
    const float* cls1b = (const float*)d_in[22];
    const float* cls2w = (const float*)d_in[23];
    const float* cls2b = (const float*)d_in[24];

    float* h0     = (float*)d_ws;
    float* h1     = h0 + (size_t)N_NODES * HID;
    float* pooled = h1 + (size_t)N_NODES * HID;
    float* cnt    = pooled + NGRAPH * HID;            // unused (layout keep)
    int*   deg    = (int*)(cnt + NGRAPH);             // unused (layout keep)
    int*   offs   = deg + N_NODES;
    int*   bsum   = offs + (N_NODES + 1);             // unused
    int*   boff   = bsum + 256;                       // unused
    int*   csr    = boff + 256;
    unsigned short* wpe = (unsigned short*)(csr + N_EDGES);   // 16384
    unsigned short* wpf = wpe + 16384;                        // 49152
    int*   goffs  = (int*)(wpf + 49152);                      // NGRAPH+1
    int*   gcnt   = goffs + (NGRAPH + 1);                     // NBKT
    // ebin (packed u32) aliases h1: written by setup_bin, consumed by
    // offs_scatter BEFORE agg1 writes h1. 128*12288*4 B = 6.3 MB << 51.2 MB.
    unsigned* ebin = (unsigned*)h1;

    const int* src = ei;
    const int* dst = ei + N_EDGES;

    // gcnt must be zero before setup_bin's bin blocks (in-kernel zeroing
    // would race them).
    hipMemsetAsync(gcnt, 0, NBKT * sizeof(int), stream);

    // setup (weight prep + graph offsets + pooled zero) + edge binning fused:
    // trivial setup blocks finish instantly, bin gets the whole machine.
    setup_bin_kernel<<<NB_SETUP + NB_BIN, 256, 0, stream>>>(
        emb_w, wpe, fc1_w, fc2_w, wpf, batch, goffs, gcnt, pooled,
        src, dst, ebin);

    // embed standalone (r7's bin||embed fusion dragged it 44 -> 74 us)
    const int gemm_blocks = N_NODES / TILE_N;   // 3125
    embed_kernel<<<gemm_blocks, 256, 0, stream>>>(x, wpe, emb_b,
                                                  ibn_g, ibn_b, ibn_m, ibn_v, h0);

    // fused offs + scatter (one ebin read, LDS-staged)
    offs_scatter_kernel<<<NBKT, 512, 0, stream>>>(gcnt, ebin, offs, csr);

    const float* hin = h0;
    float* hout = h1;
    for (int i = 0; i < 3; i++) {
        if (i < 2)
            agg_mlp_kernel<false><<<gemm_blocks, 256, 0, stream>>>(
                hin, hout, offs, csr, batch, pooled,
                wpf + (size_t)(i * 2 + 0) * 8192, wpf + (size_t)(i * 2 + 1) * 8192,
                fc1_b + i * HID, mbn_g + i * HID, mbn_b + i * HID, mbn_m + i * HID, mbn_v + i * HID,
                fc2_b + i * HID, obn_g + i * HID, obn_b + i * HID, obn_m + i * HID, obn_v + i * HID);
        else
            agg_mlp_kernel<true><<<gemm_blocks, 256, 0, stream>>>(
                hin, hout, offs, csr, batch, pooled,
                wpf + (size_t)(i * 2 + 0) * 8192, wpf + (size_t)(i * 2 + 1) * 8192,
                fc1_b + i * HID, mbn_g + i * HID, mbn_b + i * HID, mbn_m + i * HID, mbn_v + i * HID,
                fc2_b + i * HID, obn_g + i * HID, obn_b + i * HID, obn_m + i * HID, obn_v + i * HID);
        const float* tmp = hin; hin = hout; hout = (float*)tmp;
    }

    cls_kernel<<<NGRAPH, 64, 0, stream>>>(pooled, goffs, cls1w, cls1b, cls2w, cls2b,
                                          (float*)d_out);
}